// Round 7
// baseline (1814.478 us; speedup 1.0000x reference)
//
#include <hip/hip_runtime.h>

// LSTM autoencoder B=2048,T=128: L1 LSTM(128,in1) -> L2 LSTM(64,in128) -> Repeat
// -> L3 LSTM(64,in64) -> L4 LSTM(128,in64) -> Dense(1).
// R20 = R15 serial structure (best: 486us) + 2 BLOCKS PER CU via RPB=4.
// Evidence: R18 (1310us) and R19 (725us) falsify cross-layer wave pipelining in
// both work splits (R19: VGPR 80 crippled load pipelining; shared-pipe
// contention under max-of-groups barrier). The unexploited facts: grid=128 on
// 256 CUs (half the chip idle) + ~55% no-issue within a block (schedulable
// slack). RPB=4 -> grid=512 -> 2 co-resident blocks/CU interleave each other's
// stalls. Cost: 4x MFMA inflation (B-tile rows 4/16 valid; row-isolated: C row
// r depends only on B row r; dead rows bounded by LSTM gate math, never
// stored out) and 2x VALU per CU - both under pipe ceilings (MfmaUtil ~10->~35,
// VALUBusy ~33->~65 predicted). LDS 36.8KB x2 = 74KB fits; launch_bounds
// (512,4) caps VGPR at 128 so 16 waves/CU co-reside.
// Serial step structure, cvtpk gates, weights from global (R17: LDS staging
// neutral) all unchanged from the 486us baseline.

#define TSEQ 128
#define NTH  512
#define RPB  4     // rows per block (B-tile rows used of 16)
#define BSTR 408   // bU row stride in shorts

typedef __attribute__((ext_vector_type(8))) short bf16x8;
typedef __attribute__((ext_vector_type(4))) float f32x4;
typedef __attribute__((ext_vector_type(2))) float f32x2;
typedef __attribute__((ext_vector_type(4))) short s16x4;
typedef unsigned short ushort_t;

// frag regions in d_ws (units of 512-elem frags, 1KB each); hi even, lo odd (lo unused)
#define FB_L1 0      // U1: K=128 (KT=4), JT=32 -> 256 frags
#define FB_L2 256    // [W2;U2]: K=192 (KT=6), JT=16 -> 192
#define FB_L3 448    // U3: K=64 (KT=2), JT=16 -> 64
#define FB_L4 512    // [W4;U4]: K=192 (KT=6), JT=32 -> 384
#define FB_W3 896    // W3: K=64 (KT=2), JT=16 -> 64
#define WS_FRAGS 960
#define WS_NEEDED (WS_FRAGS * 1024)

__device__ __forceinline__ ushort_t f2bf(float f) {
    union { float f; unsigned u; } a; a.f = f;
    unsigned r = a.u + 0x7FFF + ((a.u >> 16) & 1);
    return (ushort_t)(r >> 16);
}
__device__ __forceinline__ float bf2f(ushort_t h) {
    union { unsigned u; float f; } a; a.u = ((unsigned)h) << 16;
    return a.f;
}
__device__ __forceinline__ float sigm(float z) { return 1.0f / (1.0f + __expf(-z)); }

__device__ __forceinline__ f32x4 MF(bf16x8 a, bf16x8 b, f32x4 c) {
    return __builtin_amdgcn_mfma_f32_16x16x32_bf16(a, b, c, 0, 0, 0);
}

// packed f32x2 -> bf16x2 (RNE), 1 instruction; dst[15:0]=lo, dst[31:16]=hi
__device__ __forceinline__ unsigned cvtpk(float lo, float hi) {
    unsigned r;
    asm("v_cvt_pk_bf16_f32 %0, %1, %2" : "=v"(r) : "v"(lo), "v"(hi));
    return r;
}

// ---------------- weight pack kernel (unchanged layout) ----------------
__global__ void pack_weights(const float* __restrict__ U1, const float* __restrict__ W2,
                             const float* __restrict__ U2, const float* __restrict__ U3,
                             const float* __restrict__ W4, const float* __restrict__ U4,
                             const float* __restrict__ W3, ushort_t* __restrict__ out)
{
    const int f = blockIdx.x;
    const int lane = threadIdx.x;
    int fl, KT, ldm, ksplit = 1 << 30, ld2 = 0;
    const float *base, *base2 = nullptr;
    if (f < 256)      { fl = f;       KT = 4; ldm = 512; base = U1; }
    else if (f < 448) { fl = f - 256; KT = 6; ldm = 256; base = W2; ksplit = 128; base2 = U2; ld2 = 256; }
    else if (f < 512) { fl = f - 448; KT = 2; ldm = 256; base = U3; }
    else if (f < 896) { fl = f - 512; KT = 6; ldm = 512; base = W4; ksplit = 64;  base2 = U4; ld2 = 512; }
    else              { fl = f - 896; KT = 2; ldm = 256; base = W3; }
    const int jt = fl / (KT * 2);
    const int rem = fl % (KT * 2);
    const int kt = rem >> 1;
    const int s = rem & 1;
    const int j = jt * 16 + (lane & 15);
    ushort_t* o = out + f * 512 + lane * 8;
    #pragma unroll
    for (int i = 0; i < 8; ++i) {
        const int k = kt * 32 + (lane >> 4) * 8 + i;
        const float w = (k < ksplit) ? base[k * ldm + j] : base2[(k - ksplit) * ld2 + j];
        const ushort_t hi = f2bf(w);
        o[i] = s ? f2bf(w - bf2f(hi)) : hi;
    }
}

// ---------------- main kernel ----------------
__global__ __launch_bounds__(NTH, 4) void lstm_mfma_kernel(
    const float* __restrict__ x,
    const float* __restrict__ W1, const float* __restrict__ b1,
    const float* __restrict__ b2, const float* __restrict__ b3,
    const float* __restrict__ b4,
    const float* __restrict__ Wd, const float* __restrict__ bd,
    const ushort_t* __restrict__ wsp,
    float* __restrict__ out)
{
    // bU: single bf16 activation plane:
    //  phaseA: h1 ping[0,128)/pong[128,256), h2 ping[256,320)/pong[320,384)
    //  phaseB: h3 ping[0,64)/pong[64,128), h4 ping[128,256)/pong[256,384)
    // Rows >= RPB are "dead" (bounded garbage, row-isolated, never stored out).
    __shared__ __align__(16) ushort_t bU[16][BSTR];      // 13056 B
    __shared__ __align__(16) float obuf[16][128];        //  8192 B
    __shared__ __align__(16) float xls[16][132];         //  8448 B
    __shared__ __align__(16) float w1ls[512], b1ls[512], b4ls[512], b2ls[256];

    const int tid  = threadIdx.x;
    const int wid  = tid >> 6;
    const int lane = tid & 63;
    const int quad = lane >> 4;
    const int l15  = lane & 15;
    const int r0   = blockIdx.x * RPB;
    const bf16x8* A = (const bf16x8*)wsp;

    // ---- init: zero state, stage x (valid rows; dead rows = 0) / W1 / biases ----
    {
        unsigned* p = (unsigned*)&bU[0][0];
        for (int i = tid; i < 16 * BSTR / 2; i += NTH) p[i] = 0u;
        const int srow = tid >> 5, scol = (tid & 31) * 4;
        f32x4 xv = {0.f, 0.f, 0.f, 0.f};
        if (srow < RPB) xv = *(const f32x4*)&x[(r0 + srow) * TSEQ + scol];
        *(f32x4*)&xls[srow][scol] = xv;
        w1ls[tid] = W1[tid];
        b1ls[tid] = b1[tid];
        b4ls[tid] = b4[tid];
        if (tid < 256) b2ls[tid] = b2[tid];
    }

    const int hcb = 16 * wid + quad * 4;   // j base within gate for 512-wide layers
    const float wd0 = Wd[lane], wd1 = Wd[64 + lane], bd0 = bd[0];

    float c1r[4] = {0.f, 0.f, 0.f, 0.f};
    float c4r[4] = {0.f, 0.f, 0.f, 0.f};

    __syncthreads();

    // ================= Phase A (ONE barrier per t) =================
    {
        float c2r[4] = {0.f, 0.f, 0.f, 0.f};

        for (int t = 0; t < TSEQ; ++t) {
            const int rb1 = (t & 1) * 128, wb1 = 128 - rb1;
            const int h2w = 256 + (t & 1) * 64;            // write buffer this t
            const int h2r = 256 + (((t & 1) ^ 1)) * 64;    // = h2w(t-1); t=0 -> 320 (zeros)

            // ---- L1: all 8 waves, MFMA + in-register gates ----
            {
                bf16x8 Bh[4];
                #pragma unroll
                for (int kt = 0; kt < 4; ++kt)
                    Bh[kt] = *(const bf16x8*)&bU[l15][rb1 + kt * 32 + quad * 8];
                const float xr = xls[l15][t];
                f32x4 acc[4];
                #pragma unroll
                for (int q = 0; q < 4; ++q) {
                    const int jb = (wid + 8 * q) * 16 + quad * 4;
                    f32x4 a = *(const f32x4*)&b1ls[jb];
                    a += xr * *(const f32x4*)&w1ls[jb];
                    #pragma unroll
                    for (int kt = 0; kt < 4; ++kt)
                        a = MF(A[(FB_L1 + ((wid + 8 * q) * 4 + kt) * 2) * 64 + lane], Bh[kt], a);
                    acc[q] = a;
                }
                float hg[4];
                #pragma unroll
                for (int g = 0; g < 4; ++g) {
                    const float zi = acc[0][g];
                    const float zf = acc[1][g];
                    const float zg = acc[2][g];
                    const float zo = acc[3][g];
                    const float c = sigm(zf) * c1r[g] + sigm(zi) * fmaxf(zg, 0.f);
                    c1r[g] = c;
                    hg[g] = sigm(zo) * fmaxf(c, 0.f);
                }
                uint2 hv;
                hv.x = cvtpk(hg[0], hg[1]);
                hv.y = cvtpk(hg[2], hg[3]);
                *(uint2*)&bU[l15][wb1 + hcb] = hv;
            }
            __syncthreads();

            // ---- L2: waves 0-3 only (1/SIMD), fused MFMA + in-register gates ----
            if (wid < 4) {
                bf16x8 Bh[6];
                #pragma unroll
                for (int kt = 0; kt < 4; ++kt)
                    Bh[kt] = *(const bf16x8*)&bU[l15][wb1 + kt * 32 + quad * 8];
                Bh[4] = *(const bf16x8*)&bU[l15][h2r + quad * 8];
                Bh[5] = *(const bf16x8*)&bU[l15][h2r + 32 + quad * 8];
                f32x4 acc[4];
                #pragma unroll
                for (int g = 0; g < 4; ++g) {
                    f32x4 a = *(const f32x4*)&b2ls[(4 * g + wid) * 16 + quad * 4];
                    #pragma unroll
                    for (int kt = 0; kt < 6; ++kt)
                        a = MF(A[(FB_L2 + ((4 * g + wid) * 6 + kt) * 2) * 64 + lane], Bh[kt], a);
                    acc[g] = a;
                }
                float hg[4];
                #pragma unroll
                for (int e = 0; e < 4; ++e) {
                    const float zi = acc[0][e];
                    const float zf = acc[1][e];
                    const float zg = acc[2][e];
                    const float zo = acc[3][e];
                    const float c = sigm(zf) * c2r[e] + sigm(zi) * fmaxf(zg, 0.f);
                    c2r[e] = c;
                    hg[e] = sigm(zo) * fmaxf(c, 0.f);
                }
                uint2 hv;
                hv.x = cvtpk(hg[0], hg[1]);
                hv.y = cvtpk(hg[2], hg[3]);
                *(uint2*)&bU[l15][h2w + wid * 16 + quad * 4] = hv;
            }
            // no trailing barrier: next-iter barrier covers all cross-wave hazards
        }
    }
    __syncthreads();

    // ================= z3r = b3 + h2_final @ W3 (registers, waves 0-3) =========
    // h2(127) is in buffer 320 (t=127 odd -> h2w=320).
    f32x4 z3r[4];
    if (wid < 4) {
        const bf16x8 Bh0 = *(const bf16x8*)&bU[l15][320 + quad * 8];
        const bf16x8 Bh1 = *(const bf16x8*)&bU[l15][320 + 32 + quad * 8];
        #pragma unroll
        for (int g = 0; g < 4; ++g) {
            const int jt = 4 * g + wid;
            f32x4 a = *(const f32x4*)&b3[jt * 16 + quad * 4];
            a = MF(A[(FB_W3 + (jt * 2 + 0) * 2) * 64 + lane], Bh0, a);
            a = MF(A[(FB_W3 + (jt * 2 + 1) * 2) * 64 + lane], Bh1, a);
            z3r[g] = a;
        }
    }
    __syncthreads();
    // re-zero activation plane + c-state for phase B
    {
        unsigned* p = (unsigned*)&bU[0][0];
        for (int i = tid; i < 16 * BSTR / 2; i += NTH) p[i] = 0u;
        c4r[0] = c4r[1] = c4r[2] = c4r[3] = 0.f;
    }
    __syncthreads();

    // ================= Phase B (ONE barrier per t) =================
    {
        float c3r[4] = {0.f, 0.f, 0.f, 0.f};

        for (int t = 0; t < TSEQ; ++t) {
            const int rb3 = (t & 1) * 64, wb3 = 64 - rb3;
            const int rb4 = 128 + (t & 1) * 128;
            const int wb4 = (rb4 == 128) ? 256 : 128;

            // ---- L3: waves 0-3 only, fused; acc init = z3r (carries b3+W3·h2) ----
            if (wid < 4) {
                const bf16x8 Bh0 = *(const bf16x8*)&bU[l15][rb3 + quad * 8];
                const bf16x8 Bh1 = *(const bf16x8*)&bU[l15][rb3 + 32 + quad * 8];
                f32x4 acc[4];
                #pragma unroll
                for (int g = 0; g < 4; ++g) {
                    f32x4 a = z3r[g];
                    a = MF(A[(FB_L3 + ((4 * g + wid) * 2 + 0) * 2) * 64 + lane], Bh0, a);
                    a = MF(A[(FB_L3 + ((4 * g + wid) * 2 + 1) * 2) * 64 + lane], Bh1, a);
                    acc[g] = a;
                }
                float hg[4];
                #pragma unroll
                for (int e = 0; e < 4; ++e) {
                    const float zi = acc[0][e];
                    const float zf = acc[1][e];
                    const float zg = acc[2][e];
                    const float zo = acc[3][e];
                    const float c = sigm(zf) * c3r[e] + sigm(zi) * fmaxf(zg, 0.f);
                    c3r[e] = c;
                    hg[e] = sigm(zo) * fmaxf(c, 0.f);
                }
                uint2 hv;
                hv.x = cvtpk(hg[0], hg[1]);
                hv.y = cvtpk(hg[2], hg[3]);
                *(uint2*)&bU[l15][wb3 + wid * 16 + quad * 4] = hv;
            }
            __syncthreads();

            // ---- L4: all 8 waves, K=192 = [h3_new ; h4_old], in-register gates ----
            {
                bf16x8 Bh[6];
                #pragma unroll
                for (int kt = 0; kt < 2; ++kt)
                    Bh[kt] = *(const bf16x8*)&bU[l15][wb3 + kt * 32 + quad * 8];
                #pragma unroll
                for (int kt = 2; kt < 6; ++kt)
                    Bh[kt] = *(const bf16x8*)&bU[l15][rb4 + (kt - 2) * 32 + quad * 8];
                f32x4 acc[4];
                #pragma unroll
                for (int q = 0; q < 4; ++q) {
                    f32x4 a = *(const f32x4*)&b4ls[(wid + 8 * q) * 16 + quad * 4];
                    #pragma unroll
                    for (int kt = 0; kt < 6; ++kt)
                        a = MF(A[(FB_L4 + ((wid + 8 * q) * 6 + kt) * 2) * 64 + lane], Bh[kt], a);
                    acc[q] = a;
                }
                float hg[4];
                #pragma unroll
                for (int g = 0; g < 4; ++g) {
                    const float zi = acc[0][g];
                    const float zf = acc[1][g];
                    const float zg = acc[2][g];
                    const float zo = acc[3][g];
                    const float c = sigm(zf) * c4r[g] + sigm(zi) * fmaxf(zg, 0.f);
                    c4r[g] = c;
                    hg[g] = sigm(zo) * fmaxf(c, 0.f);
                }
                uint2 hv;
                hv.x = cvtpk(hg[0], hg[1]);
                hv.y = cvtpk(hg[2], hg[3]);
                *(uint2*)&bU[l15][wb4 + hcb] = hv;
            }

            // ---- dense(t-1): reads h4(t-1) at rb4 (valid rows only) ----
            if (t > 0) {
                #pragma unroll
                for (int e = 0; e < 2; ++e) {
                    const int r = wid + 8 * e;
                    if (r < RPB) {
                        const float h0 = bf2f(bU[r][rb4 + lane]);
                        const float h1_ = bf2f(bU[r][rb4 + 64 + lane]);
                        float v = h0 * wd0 + h1_ * wd1;
                        v += __shfl_down(v, 32);
                        v += __shfl_down(v, 16);
                        v += __shfl_down(v, 8);
                        v += __shfl_down(v, 4);
                        v += __shfl_down(v, 2);
                        v += __shfl_down(v, 1);
                        if (lane == 0) obuf[r][t - 1] = v + bd0;
                    }
                }
            }
            // no trailing barrier: next-iter barrier covers h3/h4 hazards
        }
    }
    __syncthreads();
    // final dense: h4_{127} at col 128 (wb4 of t=127) -> obuf
    {
        #pragma unroll
        for (int e = 0; e < 2; ++e) {
            const int r = wid + 8 * e;
            if (r < RPB) {
                const float h0 = bf2f(bU[r][128 + lane]);
                const float h1_ = bf2f(bU[r][128 + 64 + lane]);
                float v = h0 * wd0 + h1_ * wd1;
                v += __shfl_down(v, 32);
                v += __shfl_down(v, 16);
                v += __shfl_down(v, 8);
                v += __shfl_down(v, 4);
                v += __shfl_down(v, 2);
                v += __shfl_down(v, 1);
                if (lane == 0) obuf[r][127] = v + bd0;
            }
        }
    }
    __syncthreads();
    // coalesced flush: 4 floats/thread, valid rows only
    {
        const int frow = tid >> 5;
        const int fcol = (tid & 31) * 4;
        if (frow < RPB)
            *(f32x4*)&out[(r0 + frow) * TSEQ + fcol] = *(const f32x4*)&obuf[frow][fcol];
    }
}

// ---------------- fallback: round-0 fp32 kernel (known good, 4.8 ms) ----------------
#define FNT 512
#define FRPB 8
__global__ __launch_bounds__(FNT, 2) void lstm_stack_kernel(
    const float* __restrict__ x,
    const float* __restrict__ W1, const float* __restrict__ U1, const float* __restrict__ b1,
    const float* __restrict__ W2, const float* __restrict__ U2, const float* __restrict__ b2,
    const float* __restrict__ W3, const float* __restrict__ U3, const float* __restrict__ b3,
    const float* __restrict__ W4, const float* __restrict__ U4, const float* __restrict__ b4,
    const float* __restrict__ Wd, const float* __restrict__ bd,
    float* __restrict__ out)
{
    __shared__ float h1s[FRPB][128], c1s[FRPB][128];
    __shared__ float h2s[FRPB][64],  c2s[FRPB][64];
    __shared__ float h3s[FRPB][64],  c3s[FRPB][64];
    __shared__ float h4s[FRPB][128], c4s[FRPB][128];
    __shared__ float zbf[FRPB][512];
    __shared__ float z3xf[FRPB][256];
    __shared__ float xs[FRPB];

    const int tid = threadIdx.x;
    const int r0  = blockIdx.x * FRPB;
    const int jg  = tid & 255;
    const int grp = tid >> 8;
    const int rb  = grp * 4;

    {
        float* p1 = &h1s[0][0]; float* p2 = &c1s[0][0];
        float* p3 = &h4s[0][0]; float* p4 = &c4s[0][0];
        for (int i = tid; i < FRPB * 128; i += FNT) { p1[i]=0.f; p2[i]=0.f; p3[i]=0.f; p4[i]=0.f; }
        float* q1 = &h2s[0][0]; float* q2 = &c2s[0][0];
        float* q3 = &h3s[0][0]; float* q4 = &c3s[0][0];
        for (int i = tid; i < FRPB * 64; i += FNT) { q1[i]=0.f; q2[i]=0.f; q3[i]=0.f; q4[i]=0.f; }
    }
    __syncthreads();

    const float w1j = W1[tid];
    const float b1j = b1[tid];
    const float b2j = b2[jg];

    for (int t = 0; t < TSEQ; ++t) {
        if (tid < FRPB) xs[tid] = x[(r0 + tid) * TSEQ + t];
        __syncthreads();
        {
            float acc[FRPB];
            #pragma unroll
            for (int r = 0; r < FRPB; ++r) acc[r] = 0.f;
            const float* Uc = U1 + tid;
            #pragma unroll 4
            for (int k4 = 0; k4 < 32; ++k4) {
                const float u0 = Uc[(k4*4+0)*512];
                const float u1 = Uc[(k4*4+1)*512];
                const float u2 = Uc[(k4*4+2)*512];
                const float u3 = Uc[(k4*4+3)*512];
                #pragma unroll
                for (int r = 0; r < FRPB; ++r) {
                    const float4 h = ((const float4*)h1s[r])[k4];
                    acc[r] += h.x*u0 + h.y*u1 + h.z*u2 + h.w*u3;
                }
            }
            #pragma unroll
            for (int r = 0; r < FRPB; ++r) zbf[r][tid] = acc[r] + xs[r]*w1j + b1j;
        }
        __syncthreads();
        for (int e = tid; e < FRPB * 128; e += FNT) {
            const int r = e >> 7, hc = e & 127;
            const float zi = zbf[r][hc], zf = zbf[r][128+hc], zg = zbf[r][256+hc], zo = zbf[r][384+hc];
            const float c = sigm(zf)*c1s[r][hc] + sigm(zi)*fmaxf(zg, 0.f);
            c1s[r][hc] = c;
            h1s[r][hc] = sigm(zo)*fmaxf(c, 0.f);
        }
        __syncthreads();
        {
            float acc[4] = {0.f, 0.f, 0.f, 0.f};
            const float* Wc = W2 + jg;
            #pragma unroll 4
            for (int k4 = 0; k4 < 32; ++k4) {
                const float u0 = Wc[(k4*4+0)*256];
                const float u1 = Wc[(k4*4+1)*256];
                const float u2 = Wc[(k4*4+2)*256];
                const float u3 = Wc[(k4*4+3)*256];
                #pragma unroll
                for (int q = 0; q < 4; ++q) {
                    const float4 h = ((const float4*)h1s[rb+q])[k4];
                    acc[q] += h.x*u0 + h.y*u1 + h.z*u2 + h.w*u3;
                }
            }
            const float* Uc = U2 + jg;
            #pragma unroll 4
            for (int k4 = 0; k4 < 16; ++k4) {
                const float u0 = Uc[(k4*4+0)*256];
                const float u1 = Uc[(k4*4+1)*256];
                const float u2 = Uc[(k4*4+2)*256];
                const float u3 = Uc[(k4*4+3)*256];
                #pragma unroll
                for (int q = 0; q < 4; ++q) {
                    const float4 h = ((const float4*)h2s[rb+q])[k4];
                    acc[q] += h.x*u0 + h.y*u1 + h.z*u2 + h.w*u3;
                }
            }
            #pragma unroll
            for (int q = 0; q < 4; ++q) zbf[rb+q][jg] = acc[q] + b2j;
        }
        __syncthreads();
        {
            const int r = tid >> 6, hc = tid & 63;
            const float zi = zbf[r][hc], zf = zbf[r][64+hc], zg = zbf[r][128+hc], zo = zbf[r][192+hc];
            const float c = sigm(zf)*c2s[r][hc] + sigm(zi)*fmaxf(zg, 0.f);
            c2s[r][hc] = c;
            h2s[r][hc] = sigm(zo)*fmaxf(c, 0.f);
        }
        __syncthreads();
    }
    {
        float acc[4] = {0.f, 0.f, 0.f, 0.f};
        const float* Wc = W3 + jg;
        #pragma unroll 4
        for (int k4 = 0; k4 < 16; ++k4) {
            const float u0 = Wc[(k4*4+0)*256];
            const float u1 = Wc[(k4*4+1)*256];
            const float u2 = Wc[(k4*4+2)*256];
            const float u3 = Wc[(k4*4+3)*256];
            #pragma unroll
            for (int q = 0; q < 4; ++q) {
                const float4 h = ((const float4*)h2s[rb+q])[k4];
                acc[q] += h.x*u0 + h.y*u1 + h.z*u2 + h.w*u3;
            }
        }
        const float b3j = b3[jg];
        #pragma unroll
        for (int q = 0; q < 4; ++q) z3xf[rb+q][jg] = acc[q] + b3j;
    }
    __syncthreads();

    const float b4j = b4[tid];
    const float wd0 = Wd[tid & 63];
    const float wd1 = Wd[64 + (tid & 63)];
    const float bd0 = bd[0];

    for (int t = 0; t < TSEQ; ++t) {
        {
            float acc[4];
            #pragma unroll
            for (int q = 0; q < 4; ++q) acc[q] = z3xf[rb+q][jg];
            const float* Uc = U3 + jg;
            #pragma unroll 4
            for (int k4 = 0; k4 < 16; ++k4) {
                const float u0 = Uc[(k4*4+0)*256];
                const float u1 = Uc[(k4*4+1)*256];
                const float u2 = Uc[(k4*4+2)*256];
                const float u3 = Uc[(k4*4+3)*256];
                #pragma unroll
                for (int q = 0; q < 4; ++q) {
                    const float4 h = ((const float4*)h3s[rb+q])[k4];
                    acc[q] += h.x*u0 + h.y*u1 + h.z*u2 + h.w*u3;
                }
            }
            #pragma unroll
            for (int q = 0; q < 4; ++q) zbf[rb+q][jg] = acc[q];
        }
        __syncthreads();
        {
            const int r = tid >> 6, hc = tid & 63;
            const float zi = zbf[r][hc], zf = zbf[r][64+hc], zg = zbf[r][128+hc], zo = zbf[r][192+hc];
            const float c = sigm(zf)*c3s[r][hc] + sigm(zi)*fmaxf(zg, 0.f);
            c3s[r][hc] = c;
            h3s[r][hc] = sigm(zo)*fmaxf(c, 0.f);
        }
        __syncthreads();
        {
            float acc[FRPB];
            #pragma unroll
            for (int r = 0; r < FRPB; ++r) acc[r] = 0.f;
            const float* Wc = W4 + tid;
            #pragma unroll 4
            for (int k4 = 0; k4 < 16; ++k4) {
                const float u0 = Wc[(k4*4+0)*512];
                const float u1 = Wc[(k4*4+1)*512];
                const float u2 = Wc[(k4*4+2)*512];
                const float u3 = Wc[(k4*4+3)*512];
                #pragma unroll
                for (int r = 0; r < FRPB; ++r) {
                    const float4 h = ((const float4*)h3s[r])[k4];
                    acc[r] += h.x*u0 + h.y*u1 + h.z*u2 + h.w*u3;
                }
            }
            const float* Uc = U4 + tid;
            #pragma unroll 4
            for (int k4 = 0; k4 < 32; ++k4) {
                const float u0 = Uc[(k4*4+0)*512];
                const float u1 = Uc[(k4*4+1)*512];
                const float u2 = Uc[(k4*4+2)*512];
                const float u3 = Uc[(k4*4+3)*512];
                #pragma unroll
                for (int r = 0; r < FRPB; ++r) {
                    const float4 h = ((const float4*)h4s[r])[k4];
                    acc[r] += h.x*u0 + h.y*u1 + h.z*u2 + h.w*u3;
                }
            }
            #pragma unroll
            for (int r = 0; r < FRPB; ++r) zbf[r][tid] = acc[r] + b4j;
        }
        __syncthreads();
        for (int e = tid; e < FRPB * 128; e += FNT) {
            const int r = e >> 7, hc = e & 127;
            const float zi = zbf[r][hc], zf = zbf[r][128+hc], zg = zbf[r][256+hc], zo = zbf[r][384+hc];
            const float c = sigm(zf)*c4s[r][hc] + sigm(zi)*fmaxf(zg, 0.f);
            c4s[r][hc] = c;
            h4s[r][hc] = sigm(zo)*fmaxf(c, 0.f);
        }
        __syncthreads();
        {
            const int wv = tid >> 6, ln = tid & 63;
            float v = h4s[wv][ln]*wd0 + h4s[wv][64+ln]*wd1;
            v += __shfl_down(v, 32, 64);
            v += __shfl_down(v, 16, 64);
            v += __shfl_down(v,  8, 64);
            v += __shfl_down(v,  4, 64);
            v += __shfl_down(v,  2, 64);
            v += __shfl_down(v,  1, 64);
            if (ln == 0) out[(r0 + wv) * TSEQ + t] = v + bd0;
        }
    }
}

extern "C" void kernel_launch(void* const* d_in, const int* in_sizes, int n_in,
                              void* d_out, int out_size, void* d_ws, size_t ws_size,
                              hipStream_t stream) {
    const float* x  = (const float*)d_in[0];
    const float* W1 = (const float*)d_in[1];
    const float* U1 = (const float*)d_in[2];
    const float* b1 = (const float*)d_in[3];
    const float* W2 = (const float*)d_in[4];
    const float* U2 = (const float*)d_in[5];
    const float* b2 = (const float*)d_in[6];
    const float* W3 = (const float*)d_in[7];
    const float* U3 = (const float*)d_in[8];
    const float* b3 = (const float*)d_in[9];
    const float* W4 = (const float*)d_in[10];
    const float* U4 = (const float*)d_in[11];
    const float* b4 = (const float*)d_in[12];
    const float* Wd = (const float*)d_in[13];
    const float* bd = (const float*)d_in[14];
    float* out = (float*)d_out;

    if (ws_size >= (size_t)WS_NEEDED) {
        ushort_t* wsp = (ushort_t*)d_ws;
        pack_weights<<<dim3(WS_FRAGS), dim3(64), 0, stream>>>(U1, W2, U2, U3, W4, U4, W3, wsp);
        lstm_mfma_kernel<<<dim3(2048 / RPB), dim3(NTH), 0, stream>>>(
            x, W1, b1, b2, b3, b4, Wd, bd, wsp, out);
    } else {
        lstm_stack_kernel<<<dim3(2048 / FRPB), dim3(FNT), 0, stream>>>(
            x, W1, U1, b1, W2, U2, b2, W3, U3, b3, W4, U4, b4, Wd, bd, out);
    }
}

// Round 8
// 1118.424 us; speedup vs baseline: 1.6224x; 1.6224x over previous
//
#include <hip/hip_runtime.h>

// LSTM autoencoder B=2048,T=128: L1 LSTM(128,in1) -> L2 LSTM(64,in128) -> Repeat
// -> L3 LSTM(64,in64) -> L4 LSTM(128,in64) -> Dense(1).
// R21 = R20 (RPB=4, grid=512, 2 blocks/CU) with launch_bounds(512,2).
// R20 post-mortem: (512,4) made hipcc cap VGPR at 64 -> scratch spills
// (WRITE_SIZE 1MB->97MB, FETCH 2.5->416MB) — a spill catastrophe, not a test
// of co-residency (which DID engage: occupancy 45.6%). R21 reruns the same
// absmax-verified RPB=4 kernel with the (512,2) bound that R15 proved compiles
// to VGPR=120 spill-free; 120<=128 VGPR and 2x36.8KB LDS => HW co-schedules
// 2 blocks/CU. Decisive experiment: per-block weight stream is 57MB from L2
// (118 GB/s/CU at 486us = 87% of the 135 GB/s per-CU L2 port). If port-bound,
// this is null/regression -> roofline call with that arithmetic. If the ~55%
// no-issue time is schedulable latency slack, 2 co-resident blocks interleave
// stalls -> 15-30% gain (co-twin's same-address weight loads may also hit L1).

#define TSEQ 128
#define NTH  512
#define RPB  4     // rows per block (B-tile rows used of 16)
#define BSTR 408   // bU row stride in shorts

typedef __attribute__((ext_vector_type(8))) short bf16x8;
typedef __attribute__((ext_vector_type(4))) float f32x4;
typedef __attribute__((ext_vector_type(2))) float f32x2;
typedef __attribute__((ext_vector_type(4))) short s16x4;
typedef unsigned short ushort_t;

// frag regions in d_ws (units of 512-elem frags, 1KB each); hi even, lo odd (lo unused)
#define FB_L1 0      // U1: K=128 (KT=4), JT=32 -> 256 frags
#define FB_L2 256    // [W2;U2]: K=192 (KT=6), JT=16 -> 192
#define FB_L3 448    // U3: K=64 (KT=2), JT=16 -> 64
#define FB_L4 512    // [W4;U4]: K=192 (KT=6), JT=32 -> 384
#define FB_W3 896    // W3: K=64 (KT=2), JT=16 -> 64
#define WS_FRAGS 960
#define WS_NEEDED (WS_FRAGS * 1024)

__device__ __forceinline__ ushort_t f2bf(float f) {
    union { float f; unsigned u; } a; a.f = f;
    unsigned r = a.u + 0x7FFF + ((a.u >> 16) & 1);
    return (ushort_t)(r >> 16);
}
__device__ __forceinline__ float bf2f(ushort_t h) {
    union { unsigned u; float f; } a; a.u = ((unsigned)h) << 16;
    return a.f;
}
__device__ __forceinline__ float sigm(float z) { return 1.0f / (1.0f + __expf(-z)); }

__device__ __forceinline__ f32x4 MF(bf16x8 a, bf16x8 b, f32x4 c) {
    return __builtin_amdgcn_mfma_f32_16x16x32_bf16(a, b, c, 0, 0, 0);
}

// packed f32x2 -> bf16x2 (RNE), 1 instruction; dst[15:0]=lo, dst[31:16]=hi
__device__ __forceinline__ unsigned cvtpk(float lo, float hi) {
    unsigned r;
    asm("v_cvt_pk_bf16_f32 %0, %1, %2" : "=v"(r) : "v"(lo), "v"(hi));
    return r;
}

// ---------------- weight pack kernel (unchanged layout) ----------------
__global__ void pack_weights(const float* __restrict__ U1, const float* __restrict__ W2,
                             const float* __restrict__ U2, const float* __restrict__ U3,
                             const float* __restrict__ W4, const float* __restrict__ U4,
                             const float* __restrict__ W3, ushort_t* __restrict__ out)
{
    const int f = blockIdx.x;
    const int lane = threadIdx.x;
    int fl, KT, ldm, ksplit = 1 << 30, ld2 = 0;
    const float *base, *base2 = nullptr;
    if (f < 256)      { fl = f;       KT = 4; ldm = 512; base = U1; }
    else if (f < 448) { fl = f - 256; KT = 6; ldm = 256; base = W2; ksplit = 128; base2 = U2; ld2 = 256; }
    else if (f < 512) { fl = f - 448; KT = 2; ldm = 256; base = U3; }
    else if (f < 896) { fl = f - 512; KT = 6; ldm = 512; base = W4; ksplit = 64;  base2 = U4; ld2 = 512; }
    else              { fl = f - 896; KT = 2; ldm = 256; base = W3; }
    const int jt = fl / (KT * 2);
    const int rem = fl % (KT * 2);
    const int kt = rem >> 1;
    const int s = rem & 1;
    const int j = jt * 16 + (lane & 15);
    ushort_t* o = out + f * 512 + lane * 8;
    #pragma unroll
    for (int i = 0; i < 8; ++i) {
        const int k = kt * 32 + (lane >> 4) * 8 + i;
        const float w = (k < ksplit) ? base[k * ldm + j] : base2[(k - ksplit) * ld2 + j];
        const ushort_t hi = f2bf(w);
        o[i] = s ? f2bf(w - bf2f(hi)) : hi;
    }
}

// ---------------- main kernel ----------------
__global__ __launch_bounds__(NTH, 2) void lstm_mfma_kernel(
    const float* __restrict__ x,
    const float* __restrict__ W1, const float* __restrict__ b1,
    const float* __restrict__ b2, const float* __restrict__ b3,
    const float* __restrict__ b4,
    const float* __restrict__ Wd, const float* __restrict__ bd,
    const ushort_t* __restrict__ wsp,
    float* __restrict__ out)
{
    // bU: single bf16 activation plane:
    //  phaseA: h1 ping[0,128)/pong[128,256), h2 ping[256,320)/pong[320,384)
    //  phaseB: h3 ping[0,64)/pong[64,128), h4 ping[128,256)/pong[256,384)
    // Rows >= RPB are "dead" (bounded garbage, row-isolated, never stored out).
    __shared__ __align__(16) ushort_t bU[16][BSTR];      // 13056 B
    __shared__ __align__(16) float obuf[16][128];        //  8192 B
    __shared__ __align__(16) float xls[16][132];         //  8448 B
    __shared__ __align__(16) float w1ls[512], b1ls[512], b4ls[512], b2ls[256];

    const int tid  = threadIdx.x;
    const int wid  = tid >> 6;
    const int lane = tid & 63;
    const int quad = lane >> 4;
    const int l15  = lane & 15;
    const int r0   = blockIdx.x * RPB;
    const bf16x8* A = (const bf16x8*)wsp;

    // ---- init: zero state, stage x (valid rows; dead rows = 0) / W1 / biases ----
    {
        unsigned* p = (unsigned*)&bU[0][0];
        for (int i = tid; i < 16 * BSTR / 2; i += NTH) p[i] = 0u;
        const int srow = tid >> 5, scol = (tid & 31) * 4;
        f32x4 xv = {0.f, 0.f, 0.f, 0.f};
        if (srow < RPB) xv = *(const f32x4*)&x[(r0 + srow) * TSEQ + scol];
        *(f32x4*)&xls[srow][scol] = xv;
        w1ls[tid] = W1[tid];
        b1ls[tid] = b1[tid];
        b4ls[tid] = b4[tid];
        if (tid < 256) b2ls[tid] = b2[tid];
    }

    const int hcb = 16 * wid + quad * 4;   // j base within gate for 512-wide layers
    const float wd0 = Wd[lane], wd1 = Wd[64 + lane], bd0 = bd[0];

    float c1r[4] = {0.f, 0.f, 0.f, 0.f};
    float c4r[4] = {0.f, 0.f, 0.f, 0.f};

    __syncthreads();

    // ================= Phase A (ONE barrier per t) =================
    {
        float c2r[4] = {0.f, 0.f, 0.f, 0.f};

        for (int t = 0; t < TSEQ; ++t) {
            const int rb1 = (t & 1) * 128, wb1 = 128 - rb1;
            const int h2w = 256 + (t & 1) * 64;            // write buffer this t
            const int h2r = 256 + (((t & 1) ^ 1)) * 64;    // = h2w(t-1); t=0 -> 320 (zeros)

            // ---- L1: all 8 waves, MFMA + in-register gates ----
            {
                bf16x8 Bh[4];
                #pragma unroll
                for (int kt = 0; kt < 4; ++kt)
                    Bh[kt] = *(const bf16x8*)&bU[l15][rb1 + kt * 32 + quad * 8];
                const float xr = xls[l15][t];
                f32x4 acc[4];
                #pragma unroll
                for (int q = 0; q < 4; ++q) {
                    const int jb = (wid + 8 * q) * 16 + quad * 4;
                    f32x4 a = *(const f32x4*)&b1ls[jb];
                    a += xr * *(const f32x4*)&w1ls[jb];
                    #pragma unroll
                    for (int kt = 0; kt < 4; ++kt)
                        a = MF(A[(FB_L1 + ((wid + 8 * q) * 4 + kt) * 2) * 64 + lane], Bh[kt], a);
                    acc[q] = a;
                }
                float hg[4];
                #pragma unroll
                for (int g = 0; g < 4; ++g) {
                    const float zi = acc[0][g];
                    const float zf = acc[1][g];
                    const float zg = acc[2][g];
                    const float zo = acc[3][g];
                    const float c = sigm(zf) * c1r[g] + sigm(zi) * fmaxf(zg, 0.f);
                    c1r[g] = c;
                    hg[g] = sigm(zo) * fmaxf(c, 0.f);
                }
                uint2 hv;
                hv.x = cvtpk(hg[0], hg[1]);
                hv.y = cvtpk(hg[2], hg[3]);
                *(uint2*)&bU[l15][wb1 + hcb] = hv;
            }
            __syncthreads();

            // ---- L2: waves 0-3 only (1/SIMD), fused MFMA + in-register gates ----
            if (wid < 4) {
                bf16x8 Bh[6];
                #pragma unroll
                for (int kt = 0; kt < 4; ++kt)
                    Bh[kt] = *(const bf16x8*)&bU[l15][wb1 + kt * 32 + quad * 8];
                Bh[4] = *(const bf16x8*)&bU[l15][h2r + quad * 8];
                Bh[5] = *(const bf16x8*)&bU[l15][h2r + 32 + quad * 8];
                f32x4 acc[4];
                #pragma unroll
                for (int g = 0; g < 4; ++g) {
                    f32x4 a = *(const f32x4*)&b2ls[(4 * g + wid) * 16 + quad * 4];
                    #pragma unroll
                    for (int kt = 0; kt < 6; ++kt)
                        a = MF(A[(FB_L2 + ((4 * g + wid) * 6 + kt) * 2) * 64 + lane], Bh[kt], a);
                    acc[g] = a;
                }
                float hg[4];
                #pragma unroll
                for (int e = 0; e < 4; ++e) {
                    const float zi = acc[0][e];
                    const float zf = acc[1][e];
                    const float zg = acc[2][e];
                    const float zo = acc[3][e];
                    const float c = sigm(zf) * c2r[e] + sigm(zi) * fmaxf(zg, 0.f);
                    c2r[e] = c;
                    hg[e] = sigm(zo) * fmaxf(c, 0.f);
                }
                uint2 hv;
                hv.x = cvtpk(hg[0], hg[1]);
                hv.y = cvtpk(hg[2], hg[3]);
                *(uint2*)&bU[l15][h2w + wid * 16 + quad * 4] = hv;
            }
            // no trailing barrier: next-iter barrier covers all cross-wave hazards
        }
    }
    __syncthreads();

    // ================= z3r = b3 + h2_final @ W3 (registers, waves 0-3) =========
    // h2(127) is in buffer 320 (t=127 odd -> h2w=320).
    f32x4 z3r[4];
    if (wid < 4) {
        const bf16x8 Bh0 = *(const bf16x8*)&bU[l15][320 + quad * 8];
        const bf16x8 Bh1 = *(const bf16x8*)&bU[l15][320 + 32 + quad * 8];
        #pragma unroll
        for (int g = 0; g < 4; ++g) {
            const int jt = 4 * g + wid;
            f32x4 a = *(const f32x4*)&b3[jt * 16 + quad * 4];
            a = MF(A[(FB_W3 + (jt * 2 + 0) * 2) * 64 + lane], Bh0, a);
            a = MF(A[(FB_W3 + (jt * 2 + 1) * 2) * 64 + lane], Bh1, a);
            z3r[g] = a;
        }
    }
    __syncthreads();
    // re-zero activation plane + c-state for phase B
    {
        unsigned* p = (unsigned*)&bU[0][0];
        for (int i = tid; i < 16 * BSTR / 2; i += NTH) p[i] = 0u;
        c4r[0] = c4r[1] = c4r[2] = c4r[3] = 0.f;
    }
    __syncthreads();

    // ================= Phase B (ONE barrier per t) =================
    {
        float c3r[4] = {0.f, 0.f, 0.f, 0.f};

        for (int t = 0; t < TSEQ; ++t) {
            const int rb3 = (t & 1) * 64, wb3 = 64 - rb3;
            const int rb4 = 128 + (t & 1) * 128;
            const int wb4 = (rb4 == 128) ? 256 : 128;

            // ---- L3: waves 0-3 only, fused; acc init = z3r (carries b3+W3·h2) ----
            if (wid < 4) {
                const bf16x8 Bh0 = *(const bf16x8*)&bU[l15][rb3 + quad * 8];
                const bf16x8 Bh1 = *(const bf16x8*)&bU[l15][rb3 + 32 + quad * 8];
                f32x4 acc[4];
                #pragma unroll
                for (int g = 0; g < 4; ++g) {
                    f32x4 a = z3r[g];
                    a = MF(A[(FB_L3 + ((4 * g + wid) * 2 + 0) * 2) * 64 + lane], Bh0, a);
                    a = MF(A[(FB_L3 + ((4 * g + wid) * 2 + 1) * 2) * 64 + lane], Bh1, a);
                    acc[g] = a;
                }
                float hg[4];
                #pragma unroll
                for (int e = 0; e < 4; ++e) {
                    const float zi = acc[0][e];
                    const float zf = acc[1][e];
                    const float zg = acc[2][e];
                    const float zo = acc[3][e];
                    const float c = sigm(zf) * c3r[e] + sigm(zi) * fmaxf(zg, 0.f);
                    c3r[e] = c;
                    hg[e] = sigm(zo) * fmaxf(c, 0.f);
                }
                uint2 hv;
                hv.x = cvtpk(hg[0], hg[1]);
                hv.y = cvtpk(hg[2], hg[3]);
                *(uint2*)&bU[l15][wb3 + wid * 16 + quad * 4] = hv;
            }
            __syncthreads();

            // ---- L4: all 8 waves, K=192 = [h3_new ; h4_old], in-register gates ----
            {
                bf16x8 Bh[6];
                #pragma unroll
                for (int kt = 0; kt < 2; ++kt)
                    Bh[kt] = *(const bf16x8*)&bU[l15][wb3 + kt * 32 + quad * 8];
                #pragma unroll
                for (int kt = 2; kt < 6; ++kt)
                    Bh[kt] = *(const bf16x8*)&bU[l15][rb4 + (kt - 2) * 32 + quad * 8];
                f32x4 acc[4];
                #pragma unroll
                for (int q = 0; q < 4; ++q) {
                    f32x4 a = *(const f32x4*)&b4ls[(wid + 8 * q) * 16 + quad * 4];
                    #pragma unroll
                    for (int kt = 0; kt < 6; ++kt)
                        a = MF(A[(FB_L4 + ((wid + 8 * q) * 6 + kt) * 2) * 64 + lane], Bh[kt], a);
                    acc[q] = a;
                }
                float hg[4];
                #pragma unroll
                for (int g = 0; g < 4; ++g) {
                    const float zi = acc[0][g];
                    const float zf = acc[1][g];
                    const float zg = acc[2][g];
                    const float zo = acc[3][g];
                    const float c = sigm(zf) * c4r[g] + sigm(zi) * fmaxf(zg, 0.f);
                    c4r[g] = c;
                    hg[g] = sigm(zo) * fmaxf(c, 0.f);
                }
                uint2 hv;
                hv.x = cvtpk(hg[0], hg[1]);
                hv.y = cvtpk(hg[2], hg[3]);
                *(uint2*)&bU[l15][wb4 + hcb] = hv;
            }

            // ---- dense(t-1): reads h4(t-1) at rb4 (valid rows only) ----
            if (t > 0) {
                #pragma unroll
                for (int e = 0; e < 2; ++e) {
                    const int r = wid + 8 * e;
                    if (r < RPB) {
                        const float h0 = bf2f(bU[r][rb4 + lane]);
                        const float h1_ = bf2f(bU[r][rb4 + 64 + lane]);
                        float v = h0 * wd0 + h1_ * wd1;
                        v += __shfl_down(v, 32);
                        v += __shfl_down(v, 16);
                        v += __shfl_down(v, 8);
                        v += __shfl_down(v, 4);
                        v += __shfl_down(v, 2);
                        v += __shfl_down(v, 1);
                        if (lane == 0) obuf[r][t - 1] = v + bd0;
                    }
                }
            }
            // no trailing barrier: next-iter barrier covers h3/h4 hazards
        }
    }
    __syncthreads();
    // final dense: h4_{127} at col 128 (wb4 of t=127) -> obuf
    {
        #pragma unroll
        for (int e = 0; e < 2; ++e) {
            const int r = wid + 8 * e;
            if (r < RPB) {
                const float h0 = bf2f(bU[r][128 + lane]);
                const float h1_ = bf2f(bU[r][128 + 64 + lane]);
                float v = h0 * wd0 + h1_ * wd1;
                v += __shfl_down(v, 32);
                v += __shfl_down(v, 16);
                v += __shfl_down(v, 8);
                v += __shfl_down(v, 4);
                v += __shfl_down(v, 2);
                v += __shfl_down(v, 1);
                if (lane == 0) obuf[r][127] = v + bd0;
            }
        }
    }
    __syncthreads();
    // coalesced flush: 4 floats/thread, valid rows only
    {
        const int frow = tid >> 5;
        const int fcol = (tid & 31) * 4;
        if (frow < RPB)
            *(f32x4*)&out[(r0 + frow) * TSEQ + fcol] = *(const f32x4*)&obuf[frow][fcol];
    }
}

// ---------------- fallback: round-0 fp32 kernel (known good, 4.8 ms) ----------------
#define FNT 512
#define FRPB 8
__global__ __launch_bounds__(FNT, 2) void lstm_stack_kernel(
    const float* __restrict__ x,
    const float* __restrict__ W1, const float* __restrict__ U1, const float* __restrict__ b1,
    const float* __restrict__ W2, const float* __restrict__ U2, const float* __restrict__ b2,
    const float* __restrict__ W3, const float* __restrict__ U3, const float* __restrict__ b3,
    const float* __restrict__ W4, const float* __restrict__ U4, const float* __restrict__ b4,
    const float* __restrict__ Wd, const float* __restrict__ bd,
    float* __restrict__ out)
{
    __shared__ float h1s[FRPB][128], c1s[FRPB][128];
    __shared__ float h2s[FRPB][64],  c2s[FRPB][64];
    __shared__ float h3s[FRPB][64],  c3s[FRPB][64];
    __shared__ float h4s[FRPB][128], c4s[FRPB][128];
    __shared__ float zbf[FRPB][512];
    __shared__ float z3xf[FRPB][256];
    __shared__ float xs[FRPB];

    const int tid = threadIdx.x;
    const int r0  = blockIdx.x * FRPB;
    const int jg  = tid & 255;
    const int grp = tid >> 8;
    const int rb  = grp * 4;

    {
        float* p1 = &h1s[0][0]; float* p2 = &c1s[0][0];
        float* p3 = &h4s[0][0]; float* p4 = &c4s[0][0];
        for (int i = tid; i < FRPB * 128; i += FNT) { p1[i]=0.f; p2[i]=0.f; p3[i]=0.f; p4[i]=0.f; }
        float* q1 = &h2s[0][0]; float* q2 = &c2s[0][0];
        float* q3 = &h3s[0][0]; float* q4 = &c3s[0][0];
        for (int i = tid; i < FRPB * 64; i += FNT) { q1[i]=0.f; q2[i]=0.f; q3[i]=0.f; q4[i]=0.f; }
    }
    __syncthreads();

    const float w1j = W1[tid];
    const float b1j = b1[tid];
    const float b2j = b2[jg];

    for (int t = 0; t < TSEQ; ++t) {
        if (tid < FRPB) xs[tid] = x[(r0 + tid) * TSEQ + t];
        __syncthreads();
        {
            float acc[FRPB];
            #pragma unroll
            for (int r = 0; r < FRPB; ++r) acc[r] = 0.f;
            const float* Uc = U1 + tid;
            #pragma unroll 4
            for (int k4 = 0; k4 < 32; ++k4) {
                const float u0 = Uc[(k4*4+0)*512];
                const float u1 = Uc[(k4*4+1)*512];
                const float u2 = Uc[(k4*4+2)*512];
                const float u3 = Uc[(k4*4+3)*512];
                #pragma unroll
                for (int r = 0; r < FRPB; ++r) {
                    const float4 h = ((const float4*)h1s[r])[k4];
                    acc[r] += h.x*u0 + h.y*u1 + h.z*u2 + h.w*u3;
                }
            }
            #pragma unroll
            for (int r = 0; r < FRPB; ++r) zbf[r][tid] = acc[r] + xs[r]*w1j + b1j;
        }
        __syncthreads();
        for (int e = tid; e < FRPB * 128; e += FNT) {
            const int r = e >> 7, hc = e & 127;
            const float zi = zbf[r][hc], zf = zbf[r][128+hc], zg = zbf[r][256+hc], zo = zbf[r][384+hc];
            const float c = sigm(zf)*c1s[r][hc] + sigm(zi)*fmaxf(zg, 0.f);
            c1s[r][hc] = c;
            h1s[r][hc] = sigm(zo)*fmaxf(c, 0.f);
        }
        __syncthreads();
        {
            float acc[4] = {0.f, 0.f, 0.f, 0.f};
            const float* Wc = W2 + jg;
            #pragma unroll 4
            for (int k4 = 0; k4 < 32; ++k4) {
                const float u0 = Wc[(k4*4+0)*256];
                const float u1 = Wc[(k4*4+1)*256];
                const float u2 = Wc[(k4*4+2)*256];
                const float u3 = Wc[(k4*4+3)*256];
                #pragma unroll
                for (int q = 0; q < 4; ++q) {
                    const float4 h = ((const float4*)h1s[rb+q])[k4];
                    acc[q] += h.x*u0 + h.y*u1 + h.z*u2 + h.w*u3;
                }
            }
            const float* Uc = U2 + jg;
            #pragma unroll 4
            for (int k4 = 0; k4 < 16; ++k4) {
                const float u0 = Uc[(k4*4+0)*256];
                const float u1 = Uc[(k4*4+1)*256];
                const float u2 = Uc[(k4*4+2)*256];
                const float u3 = Uc[(k4*4+3)*256];
                #pragma unroll
                for (int q = 0; q < 4; ++q) {
                    const float4 h = ((const float4*)h2s[rb+q])[k4];
                    acc[q] += h.x*u0 + h.y*u1 + h.z*u2 + h.w*u3;
                }
            }
            #pragma unroll
            for (int q = 0; q < 4; ++q) zbf[rb+q][jg] = acc[q] + b2j;
        }
        __syncthreads();
        {
            const int r = tid >> 6, hc = tid & 63;
            const float zi = zbf[r][hc], zf = zbf[r][64+hc], zg = zbf[r][128+hc], zo = zbf[r][192+hc];
            const float c = sigm(zf)*c2s[r][hc] + sigm(zi)*fmaxf(zg, 0.f);
            c2s[r][hc] = c;
            h2s[r][hc] = sigm(zo)*fmaxf(c, 0.f);
        }
        __syncthreads();
    }
    {
        float acc[4] = {0.f, 0.f, 0.f, 0.f};
        const float* Wc = W3 + jg;
        #pragma unroll 4
        for (int k4 = 0; k4 < 16; ++k4) {
            const float u0 = Wc[(k4*4+0)*256];
            const float u1 = Wc[(k4*4+1)*256];
            const float u2 = Wc[(k4*4+2)*256];
            const float u3 = Wc[(k4*4+3)*256];
            #pragma unroll
            for (int q = 0; q < 4; ++q) {
                const float4 h = ((const float4*)h2s[rb+q])[k4];
                acc[q] += h.x*u0 + h.y*u1 + h.z*u2 + h.w*u3;
            }
        }
        const float b3j = b3[jg];
        #pragma unroll
        for (int q = 0; q < 4; ++q) z3xf[rb+q][jg] = acc[q] + b3j;
    }
    __syncthreads();

    const float b4j = b4[tid];
    const float wd0 = Wd[tid & 63];
    const float wd1 = Wd[64 + (tid & 63)];
    const float bd0 = bd[0];

    for (int t = 0; t < TSEQ; ++t) {
        {
            float acc[4];
            #pragma unroll
            for (int q = 0; q < 4; ++q) acc[q] = z3xf[rb+q][jg];
            const float* Uc = U3 + jg;
            #pragma unroll 4
            for (int k4 = 0; k4 < 16; ++k4) {
                const float u0 = Uc[(k4*4+0)*256];
                const float u1 = Uc[(k4*4+1)*256];
                const float u2 = Uc[(k4*4+2)*256];
                const float u3 = Uc[(k4*4+3)*256];
                #pragma unroll
                for (int q = 0; q < 4; ++q) {
                    const float4 h = ((const float4*)h3s[rb+q])[k4];
                    acc[q] += h.x*u0 + h.y*u1 + h.z*u2 + h.w*u3;
                }
            }
            #pragma unroll
            for (int q = 0; q < 4; ++q) zbf[rb+q][jg] = acc[q];
        }
        __syncthreads();
        {
            const int r = tid >> 6, hc = tid & 63;
            const float zi = zbf[r][hc], zf = zbf[r][64+hc], zg = zbf[r][128+hc], zo = zbf[r][192+hc];
            const float c = sigm(zf)*c3s[r][hc] + sigm(zi)*fmaxf(zg, 0.f);
            c3s[r][hc] = c;
            h3s[r][hc] = sigm(zo)*fmaxf(c, 0.f);
        }
        __syncthreads();
        {
            float acc[FRPB];
            #pragma unroll
            for (int r = 0; r < FRPB; ++r) acc[r] = 0.f;
            const float* Wc = W4 + tid;
            #pragma unroll 4
            for (int k4 = 0; k4 < 16; ++k4) {
                const float u0 = Wc[(k4*4+0)*512];
                const float u1 = Wc[(k4*4+1)*512];
                const float u2 = Wc[(k4*4+2)*512];
                const float u3 = Wc[(k4*4+3)*512];
                #pragma unroll
                for (int r = 0; r < FRPB; ++r) {
                    const float4 h = ((const float4*)h3s[r])[k4];
                    acc[r] += h.x*u0 + h.y*u1 + h.z*u2 + h.w*u3;
                }
            }
            const float* Uc = U4 + tid;
            #pragma unroll 4
            for (int k4 = 0; k4 < 32; ++k4) {
                const float u0 = Uc[(k4*4+0)*512];
                const float u1 = Uc[(k4*4+1)*512];
                const float u2 = Uc[(k4*4+2)*512];
                const float u3 = Uc[(k4*4+3)*512];
                #pragma unroll
                for (int r = 0; r < FRPB; ++r) {
                    const float4 h = ((const float4*)h4s[r])[k4];
                    acc[r] += h.x*u0 + h.y*u1 + h.z*u2 + h.w*u3;
                }
            }
            #pragma unroll
            for (int r = 0; r < FRPB; ++r) zbf[r][tid] = acc[r] + b4j;
        }
        __syncthreads();
        for (int e = tid; e < FRPB * 128; e += FNT) {
            const int r = e >> 7, hc = e & 127;
            const float zi = zbf[r][hc], zf = zbf[r][128+hc], zg = zbf[r][256+hc], zo = zbf[r][384+hc];
            const float c = sigm(zf)*c4s[r][hc] + sigm(zi)*fmaxf(zg, 0.f);
            c4s[r][hc] = c;
            h4s[r][hc] = sigm(zo)*fmaxf(c, 0.f);
        }
        __syncthreads();
        {
            const int wv = tid >> 6, ln = tid & 63;
            float v = h4s[wv][ln]*wd0 + h4s[wv][64+ln]*wd1;
            v += __shfl_down(v, 32, 64);
            v += __shfl_down(v, 16, 64);
            v += __shfl_down(v,  8, 64);
            v += __shfl_down(v,  4, 64);
            v += __shfl_down(v,  2, 64);
            v += __shfl_down(v,  1, 64);
            if (ln == 0) out[(r0 + wv) * TSEQ + t] = v + bd0;
        }
    }
}

extern "C" void kernel_launch(void* const* d_in, const int* in_sizes, int n_in,
                              void* d_out, int out_size, void* d_ws, size_t ws_size,
                              hipStream_t stream) {
    const float* x  = (const float*)d_in[0];
    const float* W1 = (const float*)d_in[1];
    const float* U1 = (const float*)d_in[2];
    const float* b1 = (const float*)d_in[3];
    const float* W2 = (const float*)d_in[4];
    const float* U2 = (const float*)d_in[5];
    const float* b2 = (const float*)d_in[6];
    const float* W3 = (const float*)d_in[7];
    const float* U3 = (const float*)d_in[8];
    const float* b3 = (const float*)d_in[9];
    const float* W4 = (const float*)d_in[10];
    const float* U4 = (const float*)d_in[11];
    const float* b4 = (const float*)d_in[12];
    const float* Wd = (const float*)d_in[13];
    const float* bd = (const float*)d_in[14];
    float* out = (float*)d_out;

    if (ws_size >= (size_t)WS_NEEDED) {
        ushort_t* wsp = (ushort_t*)d_ws;
        pack_weights<<<dim3(WS_FRAGS), dim3(64), 0, stream>>>(U1, W2, U2, U3, W4, U4, W3, wsp);
        lstm_mfma_kernel<<<dim3(2048 / RPB), dim3(NTH), 0, stream>>>(
            x, W1, b1, b2, b3, b4, Wd, bd, wsp, out);
    } else {
        lstm_stack_kernel<<<dim3(2048 / FRPB), dim3(FNT), 0, stream>>>(
            x, W1, U1, b1, W2, U2, b2, W3, U3, b3, W4, U4, b4, Wd, bd, out);
    }
}

// Round 9
// 635.115 us; speedup vs baseline: 2.8569x; 1.7610x over previous
//
#include <hip/hip_runtime.h>

// LSTM autoencoder B=2048,T=128: L1 LSTM(128,in1) -> L2 LSTM(64,in128) -> Repeat
// -> L3 LSTM(64,in64) -> L4 LSTM(128,in64) -> Dense(1).
// R22 = R15 serial structure (best 486us, RPB=16 restored) + LDS-staged L1
// (full 128KB) and L4 (kt 0-3, 128KB, same region reused) weights.
// Model fitting all rounds: barrier sits between L1(t) and L2(t); NO barrier
// between L2(t) and L1(t+1). Compiler hoists L2/L3's loop-invariant weight
// loads up to the draining barrier -> already hidden (explains R17 null).
// L1/L4's load sets are the un-hidden residual (explains R18's 2.7x blowup
// when L1 load count doubled on fewer waves, and R21's co-residency failure:
// latency not schedulable). This tests the never-tested {L1,L4}xLDS cell.
// To fit 160KB LDS: obuf dropped (dense -> direct global stores);
// bU 13KB + xls 8.4KB + w1/b1/b4/b2 7.2KB + wstg 128KB = 156KB.
// RPB=16, grid=128, launch_bounds(512,2) (VGPR ~120 no spill per R15/R21).

#define TSEQ 128
#define NTH  512
#define BSTR 408   // bU row stride in shorts

typedef __attribute__((ext_vector_type(8))) short bf16x8;
typedef __attribute__((ext_vector_type(4))) float f32x4;
typedef __attribute__((ext_vector_type(2))) float f32x2;
typedef __attribute__((ext_vector_type(4))) short s16x4;
typedef unsigned short ushort_t;

// frag regions in d_ws (units of 512-elem frags, 1KB each); hi even, lo odd (lo unused)
#define FB_L1 0      // U1: K=128 (KT=4), JT=32 -> 256 frags
#define FB_L2 256    // [W2;U2]: K=192 (KT=6), JT=16 -> 192
#define FB_L3 448    // U3: K=64 (KT=2), JT=16 -> 64
#define FB_L4 512    // [W4;U4]: K=192 (KT=6), JT=32 -> 384
#define FB_W3 896    // W3: K=64 (KT=2), JT=16 -> 64
#define WS_FRAGS 960
#define WS_NEEDED (WS_FRAGS * 1024)

__device__ __forceinline__ ushort_t f2bf(float f) {
    union { float f; unsigned u; } a; a.f = f;
    unsigned r = a.u + 0x7FFF + ((a.u >> 16) & 1);
    return (ushort_t)(r >> 16);
}
__device__ __forceinline__ float bf2f(ushort_t h) {
    union { unsigned u; float f; } a; a.u = ((unsigned)h) << 16;
    return a.f;
}
__device__ __forceinline__ float sigm(float z) { return 1.0f / (1.0f + __expf(-z)); }

__device__ __forceinline__ f32x4 MF(bf16x8 a, bf16x8 b, f32x4 c) {
    return __builtin_amdgcn_mfma_f32_16x16x32_bf16(a, b, c, 0, 0, 0);
}

// packed f32x2 -> bf16x2 (RNE), 1 instruction; dst[15:0]=lo, dst[31:16]=hi
__device__ __forceinline__ unsigned cvtpk(float lo, float hi) {
    unsigned r;
    asm("v_cvt_pk_bf16_f32 %0, %1, %2" : "=v"(r) : "v"(lo), "v"(hi));
    return r;
}

// ---------------- weight pack kernel (unchanged layout) ----------------
__global__ void pack_weights(const float* __restrict__ U1, const float* __restrict__ W2,
                             const float* __restrict__ U2, const float* __restrict__ U3,
                             const float* __restrict__ W4, const float* __restrict__ U4,
                             const float* __restrict__ W3, ushort_t* __restrict__ out)
{
    const int f = blockIdx.x;
    const int lane = threadIdx.x;
    int fl, KT, ldm, ksplit = 1 << 30, ld2 = 0;
    const float *base, *base2 = nullptr;
    if (f < 256)      { fl = f;       KT = 4; ldm = 512; base = U1; }
    else if (f < 448) { fl = f - 256; KT = 6; ldm = 256; base = W2; ksplit = 128; base2 = U2; ld2 = 256; }
    else if (f < 512) { fl = f - 448; KT = 2; ldm = 256; base = U3; }
    else if (f < 896) { fl = f - 512; KT = 6; ldm = 512; base = W4; ksplit = 64;  base2 = U4; ld2 = 512; }
    else              { fl = f - 896; KT = 2; ldm = 256; base = W3; }
    const int jt = fl / (KT * 2);
    const int rem = fl % (KT * 2);
    const int kt = rem >> 1;
    const int s = rem & 1;
    const int j = jt * 16 + (lane & 15);
    ushort_t* o = out + f * 512 + lane * 8;
    #pragma unroll
    for (int i = 0; i < 8; ++i) {
        const int k = kt * 32 + (lane >> 4) * 8 + i;
        const float w = (k < ksplit) ? base[k * ldm + j] : base2[(k - ksplit) * ld2 + j];
        const ushort_t hi = f2bf(w);
        o[i] = s ? f2bf(w - bf2f(hi)) : hi;
    }
}

// ---------------- main kernel ----------------
__global__ __launch_bounds__(NTH, 2) void lstm_mfma_kernel(
    const float* __restrict__ x,
    const float* __restrict__ W1, const float* __restrict__ b1,
    const float* __restrict__ b2, const float* __restrict__ b3,
    const float* __restrict__ b4,
    const float* __restrict__ Wd, const float* __restrict__ bd,
    const ushort_t* __restrict__ wsp,
    float* __restrict__ out)
{
    // bU: single bf16 activation plane:
    //  phaseA: h1 ping[0,128)/pong[128,256), h2 ping[256,320)/pong[320,384)
    //  phaseB: h3 ping[0,64)/pong[64,128), h4 ping[128,256)/pong[256,384)
    __shared__ __align__(16) ushort_t bU[16][BSTR];      // 13056 B
    __shared__ __align__(16) float xls[16][132];         //  8448 B
    __shared__ __align__(16) float w1ls[512], b1ls[512], b4ls[512], b2ls[256];
    // weight staging: phase A = L1 hi frags (128 x 1KB); phase B = L4 kt<4 (128 x 1KB)
    __shared__ __align__(16) ushort_t wstg[128 * 512];   // 131072 B
    // total: 13056+8448+7168+131072 = 159744 B <= 160 KiB

    const int tid  = threadIdx.x;
    const int wid  = tid >> 6;
    const int lane = tid & 63;
    const int quad = lane >> 4;
    const int l15  = lane & 15;
    const int r0   = blockIdx.x * 16;
    const bf16x8* A = (const bf16x8*)wsp;

    // ---- init: zero state, stage x / W1 / biases / L1 weights ----
    {
        unsigned* p = (unsigned*)&bU[0][0];
        for (int i = tid; i < 16 * BSTR / 2; i += NTH) p[i] = 0u;
        const int srow = tid >> 5, scol = (tid & 31) * 4;
        *(f32x4*)&xls[srow][scol] = *(const f32x4*)&x[(r0 + srow) * TSEQ + scol];
        w1ls[tid] = W1[tid];
        b1ls[tid] = b1[tid];
        b4ls[tid] = b4[tid];
        if (tid < 256) b2ls[tid] = b2[tid];
        // stage L1 hi frags: hi frag j lives at ws frag FB_L1 + 2j
        const ushort_t* s1 = wsp + FB_L1 * 512;
        for (int i = tid; i < 128 * 64; i += NTH) {
            const int f = i >> 6, c = (i & 63) * 8;
            *(bf16x8*)&wstg[f * 512 + c] = *(const bf16x8*)&s1[f * 1024 + c];
        }
    }

    const int hcb = 16 * wid + quad * 4;   // j base within gate for 512-wide layers
    const float wd0 = Wd[lane], wd1 = Wd[64 + lane], bd0 = bd[0];

    float c1r[4] = {0.f, 0.f, 0.f, 0.f};
    float c4r[4] = {0.f, 0.f, 0.f, 0.f};

    __syncthreads();

    // ================= Phase A (ONE barrier per t) =================
    {
        float c2r[4] = {0.f, 0.f, 0.f, 0.f};

        for (int t = 0; t < TSEQ; ++t) {
            const int rb1 = (t & 1) * 128, wb1 = 128 - rb1;
            const int h2w = 256 + (t & 1) * 64;            // write buffer this t
            const int h2r = 256 + (((t & 1) ^ 1)) * 64;    // = h2w(t-1); t=0 -> 320 (zeros)

            // ---- L1: all 8 waves, weights from LDS, in-register gates ----
            {
                bf16x8 Bh[4];
                #pragma unroll
                for (int kt = 0; kt < 4; ++kt)
                    Bh[kt] = *(const bf16x8*)&bU[l15][rb1 + kt * 32 + quad * 8];
                const float xr = xls[l15][t];
                f32x4 acc[4];
                #pragma unroll
                for (int q = 0; q < 4; ++q) {
                    const int jb = (wid + 8 * q) * 16 + quad * 4;
                    f32x4 a = *(const f32x4*)&b1ls[jb];
                    a += xr * *(const f32x4*)&w1ls[jb];
                    #pragma unroll
                    for (int kt = 0; kt < 4; ++kt) {
                        const bf16x8 w = *(const bf16x8*)&wstg[(((wid + 8 * q) << 2) + kt) * 512 + lane * 8];
                        a = MF(w, Bh[kt], a);
                    }
                    acc[q] = a;
                }
                float hg[4];
                #pragma unroll
                for (int g = 0; g < 4; ++g) {
                    const float zi = acc[0][g];
                    const float zf = acc[1][g];
                    const float zg = acc[2][g];
                    const float zo = acc[3][g];
                    const float c = sigm(zf) * c1r[g] + sigm(zi) * fmaxf(zg, 0.f);
                    c1r[g] = c;
                    hg[g] = sigm(zo) * fmaxf(c, 0.f);
                }
                uint2 hv;
                hv.x = cvtpk(hg[0], hg[1]);
                hv.y = cvtpk(hg[2], hg[3]);
                *(uint2*)&bU[l15][wb1 + hcb] = hv;
            }
            __syncthreads();

            // ---- L2: waves 0-3 only (1/SIMD), weights from global (hidden:
            //      hoistable to the draining barrier), fused gates ----
            if (wid < 4) {
                bf16x8 Bh[6];
                #pragma unroll
                for (int kt = 0; kt < 4; ++kt)
                    Bh[kt] = *(const bf16x8*)&bU[l15][wb1 + kt * 32 + quad * 8];
                Bh[4] = *(const bf16x8*)&bU[l15][h2r + quad * 8];
                Bh[5] = *(const bf16x8*)&bU[l15][h2r + 32 + quad * 8];
                f32x4 acc[4];
                #pragma unroll
                for (int g = 0; g < 4; ++g) {
                    f32x4 a = *(const f32x4*)&b2ls[(4 * g + wid) * 16 + quad * 4];
                    #pragma unroll
                    for (int kt = 0; kt < 6; ++kt)
                        a = MF(A[(FB_L2 + ((4 * g + wid) * 6 + kt) * 2) * 64 + lane], Bh[kt], a);
                    acc[g] = a;
                }
                float hg[4];
                #pragma unroll
                for (int e = 0; e < 4; ++e) {
                    const float zi = acc[0][e];
                    const float zf = acc[1][e];
                    const float zg = acc[2][e];
                    const float zo = acc[3][e];
                    const float c = sigm(zf) * c2r[e] + sigm(zi) * fmaxf(zg, 0.f);
                    c2r[e] = c;
                    hg[e] = sigm(zo) * fmaxf(c, 0.f);
                }
                uint2 hv;
                hv.x = cvtpk(hg[0], hg[1]);
                hv.y = cvtpk(hg[2], hg[3]);
                *(uint2*)&bU[l15][h2w + wid * 16 + quad * 4] = hv;
            }
            // no trailing barrier: next-iter barrier covers all cross-wave hazards
        }
    }
    __syncthreads();

    // ================= z3r = b3 + h2_final @ W3 (registers, waves 0-3) =========
    // h2(127) is in buffer 320 (t=127 odd -> h2w=320).
    f32x4 z3r[4];
    if (wid < 4) {
        const bf16x8 Bh0 = *(const bf16x8*)&bU[l15][320 + quad * 8];
        const bf16x8 Bh1 = *(const bf16x8*)&bU[l15][320 + 32 + quad * 8];
        #pragma unroll
        for (int g = 0; g < 4; ++g) {
            const int jt = 4 * g + wid;
            f32x4 a = *(const f32x4*)&b3[jt * 16 + quad * 4];
            a = MF(A[(FB_W3 + (jt * 2 + 0) * 2) * 64 + lane], Bh0, a);
            a = MF(A[(FB_W3 + (jt * 2 + 1) * 2) * 64 + lane], Bh1, a);
            z3r[g] = a;
        }
    }
    __syncthreads();
    // re-zero activation plane + c-state; restage wstg with L4 kt<4 hi frags
    {
        unsigned* p = (unsigned*)&bU[0][0];
        for (int i = tid; i < 16 * BSTR / 2; i += NTH) p[i] = 0u;
        c4r[0] = c4r[1] = c4r[2] = c4r[3] = 0.f;
        const ushort_t* s4 = wsp + FB_L4 * 512;
        for (int i = tid; i < 128 * 64; i += NTH) {
            const int f = i >> 6, c = (i & 63) * 8;   // f = jt*4 + kt, kt<4
            const int jt = f >> 2, kt = f & 3;
            *(bf16x8*)&wstg[f * 512 + c] = *(const bf16x8*)&s4[(jt * 6 + kt) * 1024 + c];
        }
    }
    __syncthreads();

    // ================= Phase B (ONE barrier per t) =================
    {
        float c3r[4] = {0.f, 0.f, 0.f, 0.f};

        for (int t = 0; t < TSEQ; ++t) {
            const int rb3 = (t & 1) * 64, wb3 = 64 - rb3;
            const int rb4 = 128 + (t & 1) * 128;
            const int wb4 = (rb4 == 128) ? 256 : 128;

            // ---- L3: waves 0-3 only, fused; acc init = z3r (carries b3+W3·h2) ----
            if (wid < 4) {
                const bf16x8 Bh0 = *(const bf16x8*)&bU[l15][rb3 + quad * 8];
                const bf16x8 Bh1 = *(const bf16x8*)&bU[l15][rb3 + 32 + quad * 8];
                f32x4 acc[4];
                #pragma unroll
                for (int g = 0; g < 4; ++g) {
                    f32x4 a = z3r[g];
                    a = MF(A[(FB_L3 + ((4 * g + wid) * 2 + 0) * 2) * 64 + lane], Bh0, a);
                    a = MF(A[(FB_L3 + ((4 * g + wid) * 2 + 1) * 2) * 64 + lane], Bh1, a);
                    acc[g] = a;
                }
                float hg[4];
                #pragma unroll
                for (int e = 0; e < 4; ++e) {
                    const float zi = acc[0][e];
                    const float zf = acc[1][e];
                    const float zg = acc[2][e];
                    const float zo = acc[3][e];
                    const float c = sigm(zf) * c3r[e] + sigm(zi) * fmaxf(zg, 0.f);
                    c3r[e] = c;
                    hg[e] = sigm(zo) * fmaxf(c, 0.f);
                }
                uint2 hv;
                hv.x = cvtpk(hg[0], hg[1]);
                hv.y = cvtpk(hg[2], hg[3]);
                *(uint2*)&bU[l15][wb3 + wid * 16 + quad * 4] = hv;
            }
            __syncthreads();

            // ---- L4: all 8 waves; kt<4 weights from LDS, kt 4-5 from global ----
            {
                bf16x8 Bh[6];
                #pragma unroll
                for (int kt = 0; kt < 2; ++kt)
                    Bh[kt] = *(const bf16x8*)&bU[l15][wb3 + kt * 32 + quad * 8];
                #pragma unroll
                for (int kt = 2; kt < 6; ++kt)
                    Bh[kt] = *(const bf16x8*)&bU[l15][rb4 + (kt - 2) * 32 + quad * 8];
                f32x4 acc[4];
                #pragma unroll
                for (int q = 0; q < 4; ++q) {
                    const int jt_ = wid + 8 * q;
                    f32x4 a = *(const f32x4*)&b4ls[jt_ * 16 + quad * 4];
                    #pragma unroll
                    for (int kt = 0; kt < 4; ++kt) {
                        const bf16x8 w = *(const bf16x8*)&wstg[((jt_ << 2) + kt) * 512 + lane * 8];
                        a = MF(w, Bh[kt], a);
                    }
                    #pragma unroll
                    for (int kt = 4; kt < 6; ++kt)
                        a = MF(A[(FB_L4 + (jt_ * 6 + kt) * 2) * 64 + lane], Bh[kt], a);
                    acc[q] = a;
                }
                float hg[4];
                #pragma unroll
                for (int g = 0; g < 4; ++g) {
                    const float zi = acc[0][g];
                    const float zf = acc[1][g];
                    const float zg = acc[2][g];
                    const float zo = acc[3][g];
                    const float c = sigm(zf) * c4r[g] + sigm(zi) * fmaxf(zg, 0.f);
                    c4r[g] = c;
                    hg[g] = sigm(zo) * fmaxf(c, 0.f);
                }
                uint2 hv;
                hv.x = cvtpk(hg[0], hg[1]);
                hv.y = cvtpk(hg[2], hg[3]);
                *(uint2*)&bU[l15][wb4 + hcb] = hv;
            }

            // ---- dense(t-1): reads h4(t-1) at rb4; direct global store ----
            if (t > 0) {
                #pragma unroll
                for (int e = 0; e < 2; ++e) {
                    const int r = wid + 8 * e;
                    const float h0 = bf2f(bU[r][rb4 + lane]);
                    const float h1_ = bf2f(bU[r][rb4 + 64 + lane]);
                    float v = h0 * wd0 + h1_ * wd1;
                    v += __shfl_down(v, 32);
                    v += __shfl_down(v, 16);
                    v += __shfl_down(v, 8);
                    v += __shfl_down(v, 4);
                    v += __shfl_down(v, 2);
                    v += __shfl_down(v, 1);
                    if (lane == 0) out[(r0 + r) * TSEQ + (t - 1)] = v + bd0;
                }
            }
            // no trailing barrier: next-iter barrier covers h3/h4 hazards
        }
    }
    __syncthreads();
    // final dense: h4_{127} at col 128 (wb4 of t=127) -> direct global store
    {
        #pragma unroll
        for (int e = 0; e < 2; ++e) {
            const int r = wid + 8 * e;
            const float h0 = bf2f(bU[r][128 + lane]);
            const float h1_ = bf2f(bU[r][128 + 64 + lane]);
            float v = h0 * wd0 + h1_ * wd1;
            v += __shfl_down(v, 32);
            v += __shfl_down(v, 16);
            v += __shfl_down(v, 8);
            v += __shfl_down(v, 4);
            v += __shfl_down(v, 2);
            v += __shfl_down(v, 1);
            if (lane == 0) out[(r0 + r) * TSEQ + 127] = v + bd0;
        }
    }
}

// ---------------- fallback: round-0 fp32 kernel (known good, 4.8 ms) ----------------
#define FNT 512
#define FRPB 8
__global__ __launch_bounds__(FNT, 2) void lstm_stack_kernel(
    const float* __restrict__ x,
    const float* __restrict__ W1, const float* __restrict__ U1, const float* __restrict__ b1,
    const float* __restrict__ W2, const float* __restrict__ U2, const float* __restrict__ b2,
    const float* __restrict__ W3, const float* __restrict__ U3, const float* __restrict__ b3,
    const float* __restrict__ W4, const float* __restrict__ U4, const float* __restrict__ b4,
    const float* __restrict__ Wd, const float* __restrict__ bd,
    float* __restrict__ out)
{
    __shared__ float h1s[FRPB][128], c1s[FRPB][128];
    __shared__ float h2s[FRPB][64],  c2s[FRPB][64];
    __shared__ float h3s[FRPB][64],  c3s[FRPB][64];
    __shared__ float h4s[FRPB][128], c4s[FRPB][128];
    __shared__ float zbf[FRPB][512];
    __shared__ float z3xf[FRPB][256];
    __shared__ float xs[FRPB];

    const int tid = threadIdx.x;
    const int r0  = blockIdx.x * FRPB;
    const int jg  = tid & 255;
    const int grp = tid >> 8;
    const int rb  = grp * 4;

    {
        float* p1 = &h1s[0][0]; float* p2 = &c1s[0][0];
        float* p3 = &h4s[0][0]; float* p4 = &c4s[0][0];
        for (int i = tid; i < FRPB * 128; i += FNT) { p1[i]=0.f; p2[i]=0.f; p3[i]=0.f; p4[i]=0.f; }
        float* q1 = &h2s[0][0]; float* q2 = &c2s[0][0];
        float* q3 = &h3s[0][0]; float* q4 = &c3s[0][0];
        for (int i = tid; i < FRPB * 64; i += FNT) { q1[i]=0.f; q2[i]=0.f; q3[i]=0.f; q4[i]=0.f; }
    }
    __syncthreads();

    const float w1j = W1[tid];
    const float b1j = b1[tid];
    const float b2j = b2[jg];

    for (int t = 0; t < TSEQ; ++t) {
        if (tid < FRPB) xs[tid] = x[(r0 + tid) * TSEQ + t];
        __syncthreads();
        {
            float acc[FRPB];
            #pragma unroll
            for (int r = 0; r < FRPB; ++r) acc[r] = 0.f;
            const float* Uc = U1 + tid;
            #pragma unroll 4
            for (int k4 = 0; k4 < 32; ++k4) {
                const float u0 = Uc[(k4*4+0)*512];
                const float u1 = Uc[(k4*4+1)*512];
                const float u2 = Uc[(k4*4+2)*512];
                const float u3 = Uc[(k4*4+3)*512];
                #pragma unroll
                for (int r = 0; r < FRPB; ++r) {
                    const float4 h = ((const float4*)h1s[r])[k4];
                    acc[r] += h.x*u0 + h.y*u1 + h.z*u2 + h.w*u3;
                }
            }
            #pragma unroll
            for (int r = 0; r < FRPB; ++r) zbf[r][tid] = acc[r] + xs[r]*w1j + b1j;
        }
        __syncthreads();
        for (int e = tid; e < FRPB * 128; e += FNT) {
            const int r = e >> 7, hc = e & 127;
            const float zi = zbf[r][hc], zf = zbf[r][128+hc], zg = zbf[r][256+hc], zo = zbf[r][384+hc];
            const float c = sigm(zf)*c1s[r][hc] + sigm(zi)*fmaxf(zg, 0.f);
            c1s[r][hc] = c;
            h1s[r][hc] = sigm(zo)*fmaxf(c, 0.f);
        }
        __syncthreads();
        {
            float acc[4] = {0.f, 0.f, 0.f, 0.f};
            const float* Wc = W2 + jg;
            #pragma unroll 4
            for (int k4 = 0; k4 < 32; ++k4) {
                const float u0 = Wc[(k4*4+0)*256];
                const float u1 = Wc[(k4*4+1)*256];
                const float u2 = Wc[(k4*4+2)*256];
                const float u3 = Wc[(k4*4+3)*256];
                #pragma unroll
                for (int q = 0; q < 4; ++q) {
                    const float4 h = ((const float4*)h1s[rb+q])[k4];
                    acc[q] += h.x*u0 + h.y*u1 + h.z*u2 + h.w*u3;
                }
            }
            const float* Uc = U2 + jg;
            #pragma unroll 4
            for (int k4 = 0; k4 < 16; ++k4) {
                const float u0 = Uc[(k4*4+0)*256];
                const float u1 = Uc[(k4*4+1)*256];
                const float u2 = Uc[(k4*4+2)*256];
                const float u3 = Uc[(k4*4+3)*256];
                #pragma unroll
                for (int q = 0; q < 4; ++q) {
                    const float4 h = ((const float4*)h2s[rb+q])[k4];
                    acc[q] += h.x*u0 + h.y*u1 + h.z*u2 + h.w*u3;
                }
            }
            #pragma unroll
            for (int q = 0; q < 4; ++q) zbf[rb+q][jg] = acc[q] + b2j;
        }
        __syncthreads();
        {
            const int r = tid >> 6, hc = tid & 63;
            const float zi = zbf[r][hc], zf = zbf[r][64+hc], zg = zbf[r][128+hc], zo = zbf[r][192+hc];
            const float c = sigm(zf)*c2s[r][hc] + sigm(zi)*fmaxf(zg, 0.f);
            c2s[r][hc] = c;
            h2s[r][hc] = sigm(zo)*fmaxf(c, 0.f);
        }
        __syncthreads();
    }
    {
        float acc[4] = {0.f, 0.f, 0.f, 0.f};
        const float* Wc = W3 + jg;
        #pragma unroll 4
        for (int k4 = 0; k4 < 16; ++k4) {
            const float u0 = Wc[(k4*4+0)*256];
            const float u1 = Wc[(k4*4+1)*256];
            const float u2 = Wc[(k4*4+2)*256];
            const float u3 = Wc[(k4*4+3)*256];
            #pragma unroll
            for (int q = 0; q < 4; ++q) {
                const float4 h = ((const float4*)h2s[rb+q])[k4];
                acc[q] += h.x*u0 + h.y*u1 + h.z*u2 + h.w*u3;
            }
        }
        const float b3j = b3[jg];
        #pragma unroll
        for (int q = 0; q < 4; ++q) z3xf[rb+q][jg] = acc[q] + b3j;
    }
    __syncthreads();

    const float b4j = b4[tid];
    const float wd0 = Wd[tid & 63];
    const float wd1 = Wd[64 + (tid & 63)];
    const float bd0 = bd[0];

    for (int t = 0; t < TSEQ; ++t) {
        {
            float acc[4];
            #pragma unroll
            for (int q = 0; q < 4; ++q) acc[q] = z3xf[rb+q][jg];
            const float* Uc = U3 + jg;
            #pragma unroll 4
            for (int k4 = 0; k4 < 16; ++k4) {
                const float u0 = Uc[(k4*4+0)*256];
                const float u1 = Uc[(k4*4+1)*256];
                const float u2 = Uc[(k4*4+2)*256];
                const float u3 = Uc[(k4*4+3)*256];
                #pragma unroll
                for (int q = 0; q < 4; ++q) {
                    const float4 h = ((const float4*)h3s[rb+q])[k4];
                    acc[q] += h.x*u0 + h.y*u1 + h.z*u2 + h.w*u3;
                }
            }
            #pragma unroll
            for (int q = 0; q < 4; ++q) zbf[rb+q][jg] = acc[q];
        }
        __syncthreads();
        {
            const int r = tid >> 6, hc = tid & 63;
            const float zi = zbf[r][hc], zf = zbf[r][64+hc], zg = zbf[r][128+hc], zo = zbf[r][192+hc];
            const float c = sigm(zf)*c3s[r][hc] + sigm(zi)*fmaxf(zg, 0.f);
            c3s[r][hc] = c;
            h3s[r][hc] = sigm(zo)*fmaxf(c, 0.f);
        }
        __syncthreads();
        {
            float acc[FRPB];
            #pragma unroll
            for (int r = 0; r < FRPB; ++r) acc[r] = 0.f;
            const float* Wc = W4 + tid;
            #pragma unroll 4
            for (int k4 = 0; k4 < 16; ++k4) {
                const float u0 = Wc[(k4*4+0)*512];
                const float u1 = Wc[(k4*4+1)*512];
                const float u2 = Wc[(k4*4+2)*512];
                const float u3 = Wc[(k4*4+3)*512];
                #pragma unroll
                for (int r = 0; r < FRPB; ++r) {
                    const float4 h = ((const float4*)h3s[r])[k4];
                    acc[r] += h.x*u0 + h.y*u1 + h.z*u2 + h.w*u3;
                }
            }
            const float* Uc = U4 + tid;
            #pragma unroll 4
            for (int k4 = 0; k4 < 32; ++k4) {
                const float u0 = Uc[(k4*4+0)*512];
                const float u1 = Uc[(k4*4+1)*512];
                const float u2 = Uc[(k4*4+2)*512];
                const float u3 = Uc[(k4*4+3)*512];
                #pragma unroll
                for (int r = 0; r < FRPB; ++r) {
                    const float4 h = ((const float4*)h4s[r])[k4];
                    acc[r] += h.x*u0 + h.y*u1 + h.z*u2 + h.w*u3;
                }
            }
            #pragma unroll
            for (int r = 0; r < FRPB; ++r) zbf[r][tid] = acc[r] + b4j;
        }
        __syncthreads();
        for (int e = tid; e < FRPB * 128; e += FNT) {
            const int r = e >> 7, hc = e & 127;
            const float zi = zbf[r][hc], zf = zbf[r][128+hc], zg = zbf[r][256+hc], zo = zbf[r][384+hc];
            const float c = sigm(zf)*c4s[r][hc] + sigm(zi)*fmaxf(zg, 0.f);
            c4s[r][hc] = c;
            h4s[r][hc] = sigm(zo)*fmaxf(c, 0.f);
        }
        __syncthreads();
        {
            const int wv = tid >> 6, ln = tid & 63;
            float v = h4s[wv][ln]*wd0 + h4s[wv][64+ln]*wd1;
            v += __shfl_down(v, 32, 64);
            v += __shfl_down(v, 16, 64);
            v += __shfl_down(v,  8, 64);
            v += __shfl_down(v,  4, 64);
            v += __shfl_down(v,  2, 64);
            v += __shfl_down(v,  1, 64);
            if (ln == 0) out[(r0 + wv) * TSEQ + t] = v + bd0;
        }
    }
}

extern "C" void kernel_launch(void* const* d_in, const int* in_sizes, int n_in,
                              void* d_out, int out_size, void* d_ws, size_t ws_size,
                              hipStream_t stream) {
    const float* x  = (const float*)d_in[0];
    const float* W1 = (const float*)d_in[1];
    const float* U1 = (const float*)d_in[2];
    const float* b1 = (const float*)d_in[3];
    const float* W2 = (const float*)d_in[4];
    const float* U2 = (const float*)d_in[5];
    const float* b2 = (const float*)d_in[6];
    const float* W3 = (const float*)d_in[7];
    const float* U3 = (const float*)d_in[8];
    const float* b3 = (const float*)d_in[9];
    const float* W4 = (const float*)d_in[10];
    const float* U4 = (const float*)d_in[11];
    const float* b4 = (const float*)d_in[12];
    const float* Wd = (const float*)d_in[13];
    const float* bd = (const float*)d_in[14];
    float* out = (float*)d_out;

    if (ws_size >= (size_t)WS_NEEDED) {
        ushort_t* wsp = (ushort_t*)d_ws;
        pack_weights<<<dim3(WS_FRAGS), dim3(64), 0, stream>>>(U1, W2, U2, U3, W4, U4, W3, wsp);
        lstm_mfma_kernel<<<dim3(2048 / 16), dim3(NTH), 0, stream>>>(
            x, W1, b1, b2, b3, b4, Wd, bd, wsp, out);
    } else {
        lstm_stack_kernel<<<dim3(2048 / FRPB), dim3(FNT), 0, stream>>>(
            x, W1, U1, b1, W2, U2, b2, W3, U3, b3, W4, U4, b4, Wd, bd, out);
    }
}

// Round 10
// 612.969 us; speedup vs baseline: 2.9601x; 1.0361x over previous
//
#include <hip/hip_runtime.h>

// LSTM autoencoder B=2048,T=128: L1 LSTM(128,in1) -> L2 LSTM(64,in128) -> Repeat
// -> L3 LSTM(64,in64) -> L4 LSTM(128,in64) -> Dense(1).
// R23 = R15 serial structure (best 486us) + GATE-INTERLEAVED WEIGHT PACK for
// L2/L3/W3 -> L2/L3 spread across all 8 waves with fused in-register gates.
// Evidence: operand-path matrix fully falsified (R14/16 regs impossible,
// R17 LDS neutral, R22 LDS-for-L1/L4 -22%; global/L2 streaming is optimal).
// The overlooked residual: work imbalance. R15 phase A critical waves 0-3 do
// L1(16 MFMA) + L2(24 MFMA) = 40 serial units while waves 4-7 do 16 and park.
// L2 sat on 4 waves because fused gates need one wave to own all 4 gates of a
// 16-col block, and the standard gate-major z layout has only 4 such blocks.
// Fix: permute L2/L3/W3 columns in pack_weights so each 16-col block holds
// [c2*4+g] (col-minor, gate-minor): one MFMA's f32x4 per lane = {zi,zf,zg,zo}
// of one (row,col). 16 blocks / 8 waves = 2 blocks/wave: L2 = 12 MFMA/wave on
// ALL waves (critical 40->28); L3 = 4 MFMA all waves (critical 32->28).
// K-sum order unchanged -> bit-identical (absmax must stay 7.15e-7).
// Same ONE-barrier/step structure, parity buffers, global weight streaming.

#define TSEQ 128
#define NTH  512
#define BSTR 408   // bU row stride in shorts

typedef __attribute__((ext_vector_type(8))) short bf16x8;
typedef __attribute__((ext_vector_type(4))) float f32x4;
typedef __attribute__((ext_vector_type(2))) float f32x2;
typedef __attribute__((ext_vector_type(4))) short s16x4;
typedef unsigned short ushort_t;

// frag regions in d_ws (units of 512-elem frags, 1KB each); hi even, lo odd (lo unused)
#define FB_L1 0      // U1: K=128 (KT=4), JT=32 -> 256 frags
#define FB_L2 256    // [W2;U2]: K=192 (KT=6), JT=16 -> 192 (gate-interleaved cols)
#define FB_L3 448    // U3: K=64 (KT=2), JT=16 -> 64 (gate-interleaved cols)
#define FB_L4 512    // [W4;U4]: K=192 (KT=6), JT=32 -> 384
#define FB_W3 896    // W3: K=64 (KT=2), JT=16 -> 64 (gate-interleaved cols)
#define WS_FRAGS 960
#define WS_NEEDED (WS_FRAGS * 1024)

__device__ __forceinline__ ushort_t f2bf(float f) {
    union { float f; unsigned u; } a; a.f = f;
    unsigned r = a.u + 0x7FFF + ((a.u >> 16) & 1);
    return (ushort_t)(r >> 16);
}
__device__ __forceinline__ float bf2f(ushort_t h) {
    union { unsigned u; float f; } a; a.u = ((unsigned)h) << 16;
    return a.f;
}
__device__ __forceinline__ float sigm(float z) { return 1.0f / (1.0f + __expf(-z)); }

__device__ __forceinline__ f32x4 MF(bf16x8 a, bf16x8 b, f32x4 c) {
    return __builtin_amdgcn_mfma_f32_16x16x32_bf16(a, b, c, 0, 0, 0);
}

// packed f32x2 -> bf16x2 (RNE), 1 instruction; dst[15:0]=lo, dst[31:16]=hi
__device__ __forceinline__ unsigned cvtpk(float lo, float hi) {
    unsigned r;
    asm("v_cvt_pk_bf16_f32 %0, %1, %2" : "=v"(r) : "v"(lo), "v"(hi));
    return r;
}

// ---------------- weight pack kernel ----------------
// L2/L3/W3 regions use gate-interleaved column layout: within 16-col block b,
// position p = c2*4 + g maps to standard col g*64 + b*4 + c2 (g=gate, c2=subcol).
__global__ void pack_weights(const float* __restrict__ U1, const float* __restrict__ W2,
                             const float* __restrict__ U2, const float* __restrict__ U3,
                             const float* __restrict__ W4, const float* __restrict__ U4,
                             const float* __restrict__ W3, ushort_t* __restrict__ out)
{
    const int f = blockIdx.x;
    const int lane = threadIdx.x;
    int fl, KT, ldm, ksplit = 1 << 30, ld2 = 0;
    bool perm = false;
    const float *base, *base2 = nullptr;
    if (f < 256)      { fl = f;       KT = 4; ldm = 512; base = U1; }
    else if (f < 448) { fl = f - 256; KT = 6; ldm = 256; base = W2; ksplit = 128; base2 = U2; ld2 = 256; perm = true; }
    else if (f < 512) { fl = f - 448; KT = 2; ldm = 256; base = U3; perm = true; }
    else if (f < 896) { fl = f - 512; KT = 6; ldm = 512; base = W4; ksplit = 64;  base2 = U4; ld2 = 512; }
    else              { fl = f - 896; KT = 2; ldm = 256; base = W3; perm = true; }
    const int jt = fl / (KT * 2);
    const int rem = fl % (KT * 2);
    const int kt = rem >> 1;
    const int s = rem & 1;
    const int p = lane & 15;
    int j;
    if (perm) { const int g = p & 3, c2 = p >> 2; j = g * 64 + jt * 4 + c2; }
    else      { j = jt * 16 + p; }
    ushort_t* o = out + f * 512 + lane * 8;
    #pragma unroll
    for (int i = 0; i < 8; ++i) {
        const int k = kt * 32 + (lane >> 4) * 8 + i;
        const float w = (k < ksplit) ? base[k * ldm + j] : base2[(k - ksplit) * ld2 + j];
        const ushort_t hi = f2bf(w);
        o[i] = s ? f2bf(w - bf2f(hi)) : hi;
    }
}

// ---------------- main kernel ----------------
__global__ __launch_bounds__(NTH, 2) void lstm_mfma_kernel(
    const float* __restrict__ x,
    const float* __restrict__ W1, const float* __restrict__ b1,
    const float* __restrict__ b2, const float* __restrict__ b3,
    const float* __restrict__ b4,
    const float* __restrict__ Wd, const float* __restrict__ bd,
    const ushort_t* __restrict__ wsp,
    float* __restrict__ out)
{
    // bU: single bf16 activation plane:
    //  phaseA: h1 ping[0,128)/pong[128,256), h2 ping[256,320)/pong[320,384)
    //  phaseB: h3 ping[0,64)/pong[64,128), h4 ping[128,256)/pong[256,384)
    __shared__ __align__(16) ushort_t bU[16][BSTR];      // 13056 B
    __shared__ __align__(16) float obuf[16][128];        //  8192 B
    __shared__ __align__(16) float xls[16][132];         //  8448 B
    __shared__ __align__(16) float w1ls[512], b1ls[512], b4ls[512], b2ls[256];

    const int tid  = threadIdx.x;
    const int wid  = tid >> 6;
    const int lane = tid & 63;
    const int quad = lane >> 4;
    const int l15  = lane & 15;
    const int r0   = blockIdx.x * 16;
    const bf16x8* A = (const bf16x8*)wsp;

    // ---- init: zero state, stage x / W1 / biases (b2 gate-interleaved) ----
    {
        unsigned* p = (unsigned*)&bU[0][0];
        for (int i = tid; i < 16 * BSTR / 2; i += NTH) p[i] = 0u;
        const int srow = tid >> 5, scol = (tid & 31) * 4;
        *(f32x4*)&xls[srow][scol] = *(const f32x4*)&x[(r0 + srow) * TSEQ + scol];
        w1ls[tid] = W1[tid];
        b1ls[tid] = b1[tid];
        b4ls[tid] = b4[tid];
        if (tid < 256) {
            const int blk = tid >> 4, pp = tid & 15, c2 = pp >> 2, g = pp & 3;
            b2ls[tid] = b2[g * 64 + blk * 4 + c2];
        }
    }

    const int hcb = 16 * wid + quad * 4;   // j base within gate for 512-wide layers
    const float wd0 = Wd[lane], wd1 = Wd[64 + lane], bd0 = bd[0];

    float c1r[4] = {0.f, 0.f, 0.f, 0.f};
    float c4r[4] = {0.f, 0.f, 0.f, 0.f};

    __syncthreads();

    // ================= Phase A (ONE barrier per t; L1+L2 on ALL 8 waves) ======
    {
        float c2r[2] = {0.f, 0.f};   // per-thread c2 state, one per owned block

        for (int t = 0; t < TSEQ; ++t) {
            const int rb1 = (t & 1) * 128, wb1 = 128 - rb1;
            const int h2w = 256 + (t & 1) * 64;            // write buffer this t
            const int h2r = 256 + (((t & 1) ^ 1)) * 64;    // = h2w(t-1); t=0 -> 320 (zeros)

            // ---- L1: all 8 waves, MFMA + in-register gates (unchanged) ----
            {
                bf16x8 Bh[4];
                #pragma unroll
                for (int kt = 0; kt < 4; ++kt)
                    Bh[kt] = *(const bf16x8*)&bU[l15][rb1 + kt * 32 + quad * 8];
                const float xr = xls[l15][t];
                f32x4 acc[4];
                #pragma unroll
                for (int q = 0; q < 4; ++q) {
                    const int jb = (wid + 8 * q) * 16 + quad * 4;
                    f32x4 a = *(const f32x4*)&b1ls[jb];
                    a += xr * *(const f32x4*)&w1ls[jb];
                    #pragma unroll
                    for (int kt = 0; kt < 4; ++kt)
                        a = MF(A[(FB_L1 + ((wid + 8 * q) * 4 + kt) * 2) * 64 + lane], Bh[kt], a);
                    acc[q] = a;
                }
                float hg[4];
                #pragma unroll
                for (int g = 0; g < 4; ++g) {
                    const float zi = acc[0][g];
                    const float zf = acc[1][g];
                    const float zg = acc[2][g];
                    const float zo = acc[3][g];
                    const float c = sigm(zf) * c1r[g] + sigm(zi) * fmaxf(zg, 0.f);
                    c1r[g] = c;
                    hg[g] = sigm(zo) * fmaxf(c, 0.f);
                }
                uint2 hv;
                hv.x = cvtpk(hg[0], hg[1]);
                hv.y = cvtpk(hg[2], hg[3]);
                *(uint2*)&bU[l15][wb1 + hcb] = hv;
            }
            __syncthreads();

            // ---- L2: ALL 8 waves, 2 gate-interleaved blocks each (12 MFMA) ----
            // acc f32x4 per block = {zi,zf,zg,zo} for row l15, col b*4+quad.
            {
                bf16x8 Bh[6];
                #pragma unroll
                for (int kt = 0; kt < 4; ++kt)
                    Bh[kt] = *(const bf16x8*)&bU[l15][wb1 + kt * 32 + quad * 8];
                Bh[4] = *(const bf16x8*)&bU[l15][h2r + quad * 8];
                Bh[5] = *(const bf16x8*)&bU[l15][h2r + 32 + quad * 8];
                #pragma unroll
                for (int bb = 0; bb < 2; ++bb) {
                    const int b = 2 * wid + bb;
                    f32x4 a = *(const f32x4*)&b2ls[b * 16 + quad * 4];
                    #pragma unroll
                    for (int kt = 0; kt < 6; ++kt)
                        a = MF(A[(FB_L2 + (b * 6 + kt) * 2) * 64 + lane], Bh[kt], a);
                    const float cc = sigm(a[1]) * c2r[bb] + sigm(a[0]) * fmaxf(a[2], 0.f);
                    c2r[bb] = cc;
                    const float h = sigm(a[3]) * fmaxf(cc, 0.f);
                    bU[l15][h2w + b * 4 + quad] = f2bf(h);
                }
            }
            // no trailing barrier: next-iter barrier covers all cross-wave hazards
        }
    }
    __syncthreads();

    // ================= z3r = b3 + h2_final @ W3 (registers, ALL waves) ========
    // h2(127) is in buffer 320 (t=127 odd -> h2w=320). b3 gate-interleaved init.
    f32x4 z3r[2];
    {
        const bf16x8 Bh0 = *(const bf16x8*)&bU[l15][320 + quad * 8];
        const bf16x8 Bh1 = *(const bf16x8*)&bU[l15][320 + 32 + quad * 8];
        #pragma unroll
        for (int bb = 0; bb < 2; ++bb) {
            const int b = 2 * wid + bb;
            f32x4 a;
            #pragma unroll
            for (int j = 0; j < 4; ++j) a[j] = b3[j * 64 + b * 4 + quad];
            a = MF(A[(FB_W3 + (b * 2 + 0) * 2) * 64 + lane], Bh0, a);
            a = MF(A[(FB_W3 + (b * 2 + 1) * 2) * 64 + lane], Bh1, a);
            z3r[bb] = a;
        }
    }
    __syncthreads();
    // re-zero activation plane + c-state for phase B
    {
        unsigned* p = (unsigned*)&bU[0][0];
        for (int i = tid; i < 16 * BSTR / 2; i += NTH) p[i] = 0u;
        c4r[0] = c4r[1] = c4r[2] = c4r[3] = 0.f;
    }
    __syncthreads();

    // ================= Phase B (ONE barrier per t; L3 on ALL 8 waves) =========
    {
        float c3r[2] = {0.f, 0.f};

        for (int t = 0; t < TSEQ; ++t) {
            const int rb3 = (t & 1) * 64, wb3 = 64 - rb3;
            const int rb4 = 128 + (t & 1) * 128;
            const int wb4 = (rb4 == 128) ? 256 : 128;

            // ---- L3: ALL 8 waves, 2 gate-interleaved blocks (4 MFMA) ----
            {
                const bf16x8 Bh0 = *(const bf16x8*)&bU[l15][rb3 + quad * 8];
                const bf16x8 Bh1 = *(const bf16x8*)&bU[l15][rb3 + 32 + quad * 8];
                #pragma unroll
                for (int bb = 0; bb < 2; ++bb) {
                    const int b = 2 * wid + bb;
                    f32x4 a = z3r[bb];
                    a = MF(A[(FB_L3 + (b * 2 + 0) * 2) * 64 + lane], Bh0, a);
                    a = MF(A[(FB_L3 + (b * 2 + 1) * 2) * 64 + lane], Bh1, a);
                    const float cc = sigm(a[1]) * c3r[bb] + sigm(a[0]) * fmaxf(a[2], 0.f);
                    c3r[bb] = cc;
                    const float h = sigm(a[3]) * fmaxf(cc, 0.f);
                    bU[l15][wb3 + b * 4 + quad] = f2bf(h);
                }
            }
            __syncthreads();

            // ---- L4: all 8 waves, K=192 = [h3_new ; h4_old], in-register gates ----
            {
                bf16x8 Bh[6];
                #pragma unroll
                for (int kt = 0; kt < 2; ++kt)
                    Bh[kt] = *(const bf16x8*)&bU[l15][wb3 + kt * 32 + quad * 8];
                #pragma unroll
                for (int kt = 2; kt < 6; ++kt)
                    Bh[kt] = *(const bf16x8*)&bU[l15][rb4 + (kt - 2) * 32 + quad * 8];
                f32x4 acc[4];
                #pragma unroll
                for (int q = 0; q < 4; ++q) {
                    f32x4 a = *(const f32x4*)&b4ls[(wid + 8 * q) * 16 + quad * 4];
                    #pragma unroll
                    for (int kt = 0; kt < 6; ++kt)
                        a = MF(A[(FB_L4 + ((wid + 8 * q) * 6 + kt) * 2) * 64 + lane], Bh[kt], a);
                    acc[q] = a;
                }
                float hg[4];
                #pragma unroll
                for (int g = 0; g < 4; ++g) {
                    const float zi = acc[0][g];
                    const float zf = acc[1][g];
                    const float zg = acc[2][g];
                    const float zo = acc[3][g];
                    const float c = sigm(zf) * c4r[g] + sigm(zi) * fmaxf(zg, 0.f);
                    c4r[g] = c;
                    hg[g] = sigm(zo) * fmaxf(c, 0.f);
                }
                uint2 hv;
                hv.x = cvtpk(hg[0], hg[1]);
                hv.y = cvtpk(hg[2], hg[3]);
                *(uint2*)&bU[l15][wb4 + hcb] = hv;
            }

            // ---- dense(t-1): reads h4(t-1) at rb4 ----
            if (t > 0) {
                #pragma unroll
                for (int e = 0; e < 2; ++e) {
                    const int r = wid + 8 * e;
                    const float h0 = bf2f(bU[r][rb4 + lane]);
                    const float h1_ = bf2f(bU[r][rb4 + 64 + lane]);
                    float v = h0 * wd0 + h1_ * wd1;
                    v += __shfl_down(v, 32);
                    v += __shfl_down(v, 16);
                    v += __shfl_down(v, 8);
                    v += __shfl_down(v, 4);
                    v += __shfl_down(v, 2);
                    v += __shfl_down(v, 1);
                    if (lane == 0) obuf[r][t - 1] = v + bd0;
                }
            }
            // no trailing barrier: next-iter barrier covers h3/h4 hazards
        }
    }
    __syncthreads();
    // final dense: h4_{127} at col 128 (wb4 of t=127) -> obuf
    {
        #pragma unroll
        for (int e = 0; e < 2; ++e) {
            const int r = wid + 8 * e;
            const float h0 = bf2f(bU[r][128 + lane]);
            const float h1_ = bf2f(bU[r][128 + 64 + lane]);
            float v = h0 * wd0 + h1_ * wd1;
            v += __shfl_down(v, 32);
            v += __shfl_down(v, 16);
            v += __shfl_down(v, 8);
            v += __shfl_down(v, 4);
            v += __shfl_down(v, 2);
            v += __shfl_down(v, 1);
            if (lane == 0) obuf[r][127] = v + bd0;
        }
    }
    __syncthreads();
    // coalesced flush: 4 floats/thread
    {
        const int frow = tid >> 5;
        const int fcol = (tid & 31) * 4;
        *(f32x4*)&out[(r0 + frow) * TSEQ + fcol] = *(const f32x4*)&obuf[frow][fcol];
    }
}

// ---------------- fallback: round-0 fp32 kernel (known good, 4.8 ms) ----------------
#define FNT 512
#define FRPB 8
__global__ __launch_bounds__(FNT, 2) void lstm_stack_kernel(
    const float* __restrict__ x,
    const float* __restrict__ W1, const float* __restrict__ U1, const float* __restrict__ b1,
    const float* __restrict__ W2, const float* __restrict__ U2, const float* __restrict__ b2,
    const float* __restrict__ W3, const float* __restrict__ U3, const float* __restrict__ b3,
    const float* __restrict__ W4, const float* __restrict__ U4, const float* __restrict__ b4,
    const float* __restrict__ Wd, const float* __restrict__ bd,
    float* __restrict__ out)
{
    __shared__ float h1s[FRPB][128], c1s[FRPB][128];
    __shared__ float h2s[FRPB][64],  c2s[FRPB][64];
    __shared__ float h3s[FRPB][64],  c3s[FRPB][64];
    __shared__ float h4s[FRPB][128], c4s[FRPB][128];
    __shared__ float zbf[FRPB][512];
    __shared__ float z3xf[FRPB][256];
    __shared__ float xs[FRPB];

    const int tid = threadIdx.x;
    const int r0  = blockIdx.x * FRPB;
    const int jg  = tid & 255;
    const int grp = tid >> 8;
    const int rb  = grp * 4;

    {
        float* p1 = &h1s[0][0]; float* p2 = &c1s[0][0];
        float* p3 = &h4s[0][0]; float* p4 = &c4s[0][0];
        for (int i = tid; i < FRPB * 128; i += FNT) { p1[i]=0.f; p2[i]=0.f; p3[i]=0.f; p4[i]=0.f; }
        float* q1 = &h2s[0][0]; float* q2 = &c2s[0][0];
        float* q3 = &h3s[0][0]; float* q4 = &c3s[0][0];
        for (int i = tid; i < FRPB * 64; i += FNT) { q1[i]=0.f; q2[i]=0.f; q3[i]=0.f; q4[i]=0.f; }
    }
    __syncthreads();

    const float w1j = W1[tid];
    const float b1j = b1[tid];
    const float b2j = b2[jg];

    for (int t = 0; t < TSEQ; ++t) {
        if (tid < FRPB) xs[tid] = x[(r0 + tid) * TSEQ + t];
        __syncthreads();
        {
            float acc[FRPB];
            #pragma unroll
            for (int r = 0; r < FRPB; ++r) acc[r] = 0.f;
            const float* Uc = U1 + tid;
            #pragma unroll 4
            for (int k4 = 0; k4 < 32; ++k4) {
                const float u0 = Uc[(k4*4+0)*512];
                const float u1 = Uc[(k4*4+1)*512];
                const float u2 = Uc[(k4*4+2)*512];
                const float u3 = Uc[(k4*4+3)*512];
                #pragma unroll
                for (int r = 0; r < FRPB; ++r) {
                    const float4 h = ((const float4*)h1s[r])[k4];
                    acc[r] += h.x*u0 + h.y*u1 + h.z*u2 + h.w*u3;
                }
            }
            #pragma unroll
            for (int r = 0; r < FRPB; ++r) zbf[r][tid] = acc[r] + xs[r]*w1j + b1j;
        }
        __syncthreads();
        for (int e = tid; e < FRPB * 128; e += FNT) {
            const int r = e >> 7, hc = e & 127;
            const float zi = zbf[r][hc], zf = zbf[r][128+hc], zg = zbf[r][256+hc], zo = zbf[r][384+hc];
            const float c = sigm(zf)*c1s[r][hc] + sigm(zi)*fmaxf(zg, 0.f);
            c1s[r][hc] = c;
            h1s[r][hc] = sigm(zo)*fmaxf(c, 0.f);
        }
        __syncthreads();
        {
            float acc[4] = {0.f, 0.f, 0.f, 0.f};
            const float* Wc = W2 + jg;
            #pragma unroll 4
            for (int k4 = 0; k4 < 32; ++k4) {
                const float u0 = Wc[(k4*4+0)*256];
                const float u1 = Wc[(k4*4+1)*256];
                const float u2 = Wc[(k4*4+2)*256];
                const float u3 = Wc[(k4*4+3)*256];
                #pragma unroll
                for (int q = 0; q < 4; ++q) {
                    const float4 h = ((const float4*)h1s[rb+q])[k4];
                    acc[q] += h.x*u0 + h.y*u1 + h.z*u2 + h.w*u3;
                }
            }
            const float* Uc = U2 + jg;
            #pragma unroll 4
            for (int k4 = 0; k4 < 16; ++k4) {
                const float u0 = Uc[(k4*4+0)*256];
                const float u1 = Uc[(k4*4+1)*256];
                const float u2 = Uc[(k4*4+2)*256];
                const float u3 = Uc[(k4*4+3)*256];
                #pragma unroll
                for (int q = 0; q < 4; ++q) {
                    const float4 h = ((const float4*)h2s[rb+q])[k4];
                    acc[q] += h.x*u0 + h.y*u1 + h.z*u2 + h.w*u3;
                }
            }
            #pragma unroll
            for (int q = 0; q < 4; ++q) zbf[rb+q][jg] = acc[q] + b2j;
        }
        __syncthreads();
        {
            const int r = tid >> 6, hc = tid & 63;
            const float zi = zbf[r][hc], zf = zbf[r][64+hc], zg = zbf[r][128+hc], zo = zbf[r][192+hc];
            const float c = sigm(zf)*c2s[r][hc] + sigm(zi)*fmaxf(zg, 0.f);
            c2s[r][hc] = c;
            h2s[r][hc] = sigm(zo)*fmaxf(c, 0.f);
        }
        __syncthreads();
    }
    {
        float acc[4] = {0.f, 0.f, 0.f, 0.f};
        const float* Wc = W3 + jg;
        #pragma unroll 4
        for (int k4 = 0; k4 < 16; ++k4) {
            const float u0 = Wc[(k4*4+0)*256];
            const float u1 = Wc[(k4*4+1)*256];
            const float u2 = Wc[(k4*4+2)*256];
            const float u3 = Wc[(k4*4+3)*256];
            #pragma unroll
            for (int q = 0; q < 4; ++q) {
                const float4 h = ((const float4*)h2s[rb+q])[k4];
                acc[q] += h.x*u0 + h.y*u1 + h.z*u2 + h.w*u3;
            }
        }
        const float b3j = b3[jg];
        #pragma unroll
        for (int q = 0; q < 4; ++q) z3xf[rb+q][jg] = acc[q] + b3j;
    }
    __syncthreads();

    const float b4j = b4[tid];
    const float wd0 = Wd[tid & 63];
    const float wd1 = Wd[64 + (tid & 63)];
    const float bd0 = bd[0];

    for (int t = 0; t < TSEQ; ++t) {
        {
            float acc[4];
            #pragma unroll
            for (int q = 0; q < 4; ++q) acc[q] = z3xf[rb+q][jg];
            const float* Uc = U3 + jg;
            #pragma unroll 4
            for (int k4 = 0; k4 < 16; ++k4) {
                const float u0 = Uc[(k4*4+0)*256];
                const float u1 = Uc[(k4*4+1)*256];
                const float u2 = Uc[(k4*4+2)*256];
                const float u3 = Uc[(k4*4+3)*256];
                #pragma unroll
                for (int q = 0; q < 4; ++q) {
                    const float4 h = ((const float4*)h3s[rb+q])[k4];
                    acc[q] += h.x*u0 + h.y*u1 + h.z*u2 + h.w*u3;
                }
            }
            #pragma unroll
            for (int q = 0; q < 4; ++q) zbf[rb+q][jg] = acc[q];
        }
        __syncthreads();
        {
            const int r = tid >> 6, hc = tid & 63;
            const float zi = zbf[r][hc], zf = zbf[r][64+hc], zg = zbf[r][128+hc], zo = zbf[r][192+hc];
            const float c = sigm(zf)*c3s[r][hc] + sigm(zi)*fmaxf(zg, 0.f);
            c3s[r][hc] = c;
            h3s[r][hc] = sigm(zo)*fmaxf(c, 0.f);
        }
        __syncthreads();
        {
            float acc[FRPB];
            #pragma unroll
            for (int r = 0; r < FRPB; ++r) acc[r] = 0.f;
            const float* Wc = W4 + tid;
            #pragma unroll 4
            for (int k4 = 0; k4 < 16; ++k4) {
                const float u0 = Wc[(k4*4+0)*512];
                const float u1 = Wc[(k4*4+1)*512];
                const float u2 = Wc[(k4*4+2)*512];
                const float u3 = Wc[(k4*4+3)*512];
                #pragma unroll
                for (int r = 0; r < FRPB; ++r) {
                    const float4 h = ((const float4*)h3s[r])[k4];
                    acc[r] += h.x*u0 + h.y*u1 + h.z*u2 + h.w*u3;
                }
            }
            const float* Uc = U4 + tid;
            #pragma unroll 4
            for (int k4 = 0; k4 < 32; ++k4) {
                const float u0 = Uc[(k4*4+0)*512];
                const float u1 = Uc[(k4*4+1)*512];
                const float u2 = Uc[(k4*4+2)*512];
                const float u3 = Uc[(k4*4+3)*512];
                #pragma unroll
                for (int r = 0; r < FRPB; ++r) {
                    const float4 h = ((const float4*)h4s[r])[k4];
                    acc[r] += h.x*u0 + h.y*u1 + h.z*u2 + h.w*u3;
                }
            }
            #pragma unroll
            for (int r = 0; r < FRPB; ++r) zbf[r][tid] = acc[r] + b4j;
        }
        __syncthreads();
        for (int e = tid; e < FRPB * 128; e += FNT) {
            const int r = e >> 7, hc = e & 127;
            const float zi = zbf[r][hc], zf = zbf[r][128+hc], zg = zbf[r][256+hc], zo = zbf[r][384+hc];
            const float c = sigm(zf)*c4s[r][hc] + sigm(zi)*fmaxf(zg, 0.f);
            c4s[r][hc] = c;
            h4s[r][hc] = sigm(zo)*fmaxf(c, 0.f);
        }
        __syncthreads();
        {
            const int wv = tid >> 6, ln = tid & 63;
            float v = h4s[wv][ln]*wd0 + h4s[wv][64+ln]*wd1;
            v += __shfl_down(v, 32, 64);
            v += __shfl_down(v, 16, 64);
            v += __shfl_down(v,  8, 64);
            v += __shfl_down(v,  4, 64);
            v += __shfl_down(v,  2, 64);
            v += __shfl_down(v,  1, 64);
            if (ln == 0) out[(r0 + wv) * TSEQ + t] = v + bd0;
        }
    }
}

extern "C" void kernel_launch(void* const* d_in, const int* in_sizes, int n_in,
                              void* d_out, int out_size, void* d_ws, size_t ws_size,
                              hipStream_t stream) {
    const float* x  = (const float*)d_in[0];
    const float* W1 = (const float*)d_in[1];
    const float* U1 = (const float*)d_in[2];
    const float* b1 = (const float*)d_in[3];
    const float* W2 = (const float*)d_in[4];
    const float* U2 = (const float*)d_in[5];
    const float* b2 = (const float*)d_in[6];
    const float* W3 = (const float*)d_in[7];
    const float* U3 = (const float*)d_in[8];
    const float* b3 = (const float*)d_in[9];
    const float* W4 = (const float*)d_in[10];
    const float* U4 = (const float*)d_in[11];
    const float* b4 = (const float*)d_in[12];
    const float* Wd = (const float*)d_in[13];
    const float* bd = (const float*)d_in[14];
    float* out = (float*)d_out;

    if (ws_size >= (size_t)WS_NEEDED) {
        ushort_t* wsp = (ushort_t*)d_ws;
        pack_weights<<<dim3(WS_FRAGS), dim3(64), 0, stream>>>(U1, W2, U2, U3, W4, U4, W3, wsp);
        lstm_mfma_kernel<<<dim3(2048 / 16), dim3(NTH), 0, stream>>>(
            x, W1, b1, b2, b3, b4, Wd, bd, wsp, out);
    } else {
        lstm_stack_kernel<<<dim3(2048 / FRPB), dim3(FNT), 0, stream>>>(
            x, W1, U1, b1, W2, U2, b2, W3, U3, b3, W4, U4, b4, Wd, bd, out);
    }
}